// Round 8
// baseline (376.133 us; speedup 1.0000x reference)
//
#include <hip/hip_runtime.h>

// Problem constants (B,S,D,H from reference)
#define B_ 2
#define S_ 2048
#define D_ 1024
#define H_ 16
#define DK_ 64
#define M_ (B_ * S_)      // 4096 rows in the projection GEMMs

typedef __bf16 bf16;
typedef __attribute__((ext_vector_type(8))) __bf16 bf16x8;
typedef __attribute__((ext_vector_type(4))) __bf16 bf16x4;
typedef __attribute__((ext_vector_type(4))) float f32x4;

static __device__ __forceinline__ bf16x8 ld8(const bf16* p) {
    return *(const bf16x8*)p;   // 16B aligned by construction
}

// Async global->LDS, 16B per lane. LDS dest = wave-uniform base + lane*16
// (linear); global src is per-lane (carries the swizzle).
static __device__ __forceinline__ void g2l16(const void* g, void* l) {
    __builtin_amdgcn_global_load_lds(
        (const __attribute__((address_space(1))) unsigned int*)g,
        (__attribute__((address_space(3))) unsigned int*)l, 16, 0, 0);
}

// ---------------------------------------------------------------------------
// Elementwise fp32 -> bf16 for the 3 X inputs (into d_out scratch) and the
// 4 weight matrices (into ws). Block mapping: 3*2048 X-blocks + 4*512 W-blocks.
// ---------------------------------------------------------------------------
__global__ __launch_bounds__(256)
void cvt_all(const float* __restrict__ xq, const float* __restrict__ xk,
             const float* __restrict__ xv, const float* __restrict__ wq,
             const float* __restrict__ wk, const float* __restrict__ wv,
             const float* __restrict__ wo, bf16* __restrict__ xqo,
             bf16* __restrict__ xko, bf16* __restrict__ xvo,
             bf16* __restrict__ wqo, bf16* __restrict__ wko,
             bf16* __restrict__ wvo, bf16* __restrict__ woo)
{
    const int bx = blockIdx.x;
    const float* s; bf16* d; size_t base;
    if (bx < 6144) {
        int a = bx >> 11;
        s = (a == 0) ? xq : (a == 1) ? xk : xv;
        d = (a == 0) ? xqo : (a == 1) ? xko : xvo;
        base = (size_t)(bx & 2047) * 2048;
    } else {
        int a = (bx - 6144) >> 9;
        s = (a == 0) ? wq : (a == 1) ? wk : (a == 2) ? wv : wo;
        d = (a == 0) ? wqo : (a == 1) ? wko : (a == 2) ? wvo : woo;
        base = (size_t)((bx - 6144) & 511) * 2048;
    }
    size_t i = base + (size_t)threadIdx.x * 8;
    f32x4 a4 = *(const f32x4*)(s + i);
    f32x4 b4 = *(const f32x4*)(s + i + 4);
    bf16x8 r;
    r[0]=(bf16)a4[0]; r[1]=(bf16)a4[1]; r[2]=(bf16)a4[2]; r[3]=(bf16)a4[3];
    r[4]=(bf16)b4[0]; r[5]=(bf16)b4[1]; r[6]=(bf16)b4[2]; r[7]=(bf16)b4[3];
    *(bf16x8*)(d + i) = r;
}

// ---------------------------------------------------------------------------
// 128x128-tile bf16 GEMM, LDS-staged, 2-barrier K-loop.
// out_mode: 0 = bf16 head-split (B,H,S,DK);  1 = fp32 flat (M,N);
//           2 = bf16 V^T head-split (B,H,DK,S) with PAIR-INTERLEAVED tokens:
//               within each 32-token block, element order is
//               (j0,j0+16,j0+1,j0+17,...,j0+15,j0+31)  [pos=2*(j&15)+(j>>4)].
//               This makes attn_ctx's PV fragment one contiguous 16B read.
// a_headsplit: A element (m,k) at ((b*H+h)*S+s)*DK+dk (ctx layout).
// scale: applied after bias. Q gemm folds 0.125*log2(e) (softmax 1/sqrt(DK)
//        plus the exp->exp2 conversion factor).
// ---------------------------------------------------------------------------
__global__ __launch_bounds__(256)
void gemm128(const bf16* __restrict__ A, const bf16* __restrict__ W,
             const float* __restrict__ bias, void* __restrict__ out,
             int a_headsplit, int out_mode, float scale)
{
    const int m0 = blockIdx.x * 128, n0 = blockIdx.y * 128;
    const int tid = threadIdx.x;
    const int wv = tid >> 6, lane = tid & 63, quad = lane >> 4, l16 = lane & 15;
    const int wr = (wv >> 1) * 64, wc = (wv & 1) * 64;

    __shared__ bf16 As[128 * 32];
    __shared__ bf16 Bs[128 * 32];

    f32x4 acc[4][4];
#pragma unroll
    for (int i = 0; i < 4; ++i)
#pragma unroll
        for (int j = 0; j < 4; ++j) acc[i][j] = f32x4{0.f, 0.f, 0.f, 0.f};

    const int srow = tid >> 2;
    const int scol = (tid & 3) * 8;

    for (int k0 = 0; k0 < D_; k0 += 32) {
        bf16x8 av[2], bw[2];
#pragma unroll
        for (int c = 0; c < 2; ++c) {
            const int row = c * 64 + srow;
            const int k   = k0 + scol;
            const bf16* ap;
            if (a_headsplit) {
                int m = m0 + row, bb = m >> 11, ss = m & (S_ - 1);
                int hh = k >> 6, dd = k & (DK_ - 1);
                ap = A + (((size_t)(bb * H_ + hh) * S_ + ss) * DK_ + dd);
            } else {
                ap = A + (size_t)(m0 + row) * D_ + k;
            }
            av[c] = ld8(ap);
            bw[c] = ld8(W + (size_t)(n0 + row) * D_ + k);
        }
        __syncthreads();
#pragma unroll
        for (int c = 0; c < 2; ++c) {
            const int e = c * 2048 + tid * 8;
            *(bf16x8*)(As + e) = av[c];
            *(bf16x8*)(Bs + e) = bw[c];
        }
        __syncthreads();

        bf16x8 af[4], bfr[4];
#pragma unroll
        for (int i = 0; i < 4; ++i)
            af[i] = *(const bf16x8*)(As + (wr + i*16 + l16) * 32 + quad * 8);
#pragma unroll
        for (int j = 0; j < 4; ++j)
            bfr[j] = *(const bf16x8*)(Bs + (wc + j*16 + l16) * 32 + quad * 8);
#pragma unroll
        for (int i = 0; i < 4; ++i)
#pragma unroll
            for (int j = 0; j < 4; ++j)
                acc[i][j] = __builtin_amdgcn_mfma_f32_16x16x32_bf16(
                    af[i], bfr[j], acc[i][j], 0, 0, 0);
    }

    if (out_mode == 2) {
        // V^T pair-interleaved: i-tiles 2ip (tokens s..s+15 region) and 2ip+1
        // (s+16..s+31) share a 32-token block; interleaving their r-elements
        // gives one contiguous 16B store at pos-base 2*(s&15).
#pragma unroll
        for (int j = 0; j < 4; ++j) {
            const int nn = n0 + wc + j*16 + l16;      // d index
            const float bvv = bias[nn];
            int hh = nn >> 6, dd = nn & (DK_ - 1);
#pragma unroll
            for (int ip = 0; ip < 2; ++ip) {
                const int mlo = m0 + wr + 32*ip + quad*4;   // token of (2ip, r=0)
                int bb = mlo >> 11, sl = mlo & (S_ - 1);
                int g0 = (sl & ~31) + ((sl & 15) << 1);
                bf16x8 pk;
#pragma unroll
                for (int r = 0; r < 4; ++r) {
                    pk[2*r]   = (bf16)((acc[2*ip  ][j][r] + bvv) * scale);
                    pk[2*r+1] = (bf16)((acc[2*ip+1][j][r] + bvv) * scale);
                }
                *(bf16x8*)((bf16*)out +
                    ((size_t)(bb * H_ + hh) * DK_ + dd) * S_ + g0) = pk;
            }
        }
    } else {
#pragma unroll
        for (int i = 0; i < 4; ++i)
#pragma unroll
            for (int j = 0; j < 4; ++j) {
                const int nn = n0 + wc + j*16 + l16;
                const float bvv = bias[nn];
                const int mm0 = m0 + wr + i*16 + quad*4;   // 4-aligned, same b
#pragma unroll
                for (int r = 0; r < 4; ++r) {
                    const int mm = mm0 + r;
                    float v = (acc[i][j][r] + bvv) * scale;
                    if (out_mode == 1) {
                        ((float*)out)[(size_t)mm * D_ + nn] = v;
                    } else {
                        int bb = mm >> 11, ss = mm & (S_ - 1);
                        int hh = nn >> 6, dd = nn & (DK_ - 1);
                        ((bf16*)out)[((size_t)(bb * H_ + hh) * S_ + ss) * DK_ + dd] = (bf16)v;
                    }
                }
            }
    }
}

// ---------------------------------------------------------------------------
// Context + softmax denominators, fused.
// Block = 64 q-rows, one (h,b); 4 waves; each wave owns 16 q-rows over the
// full j-range (no cross-wave reduce). K and interleaved-V^T staged in 64-j
// chunks via global_load_lds into double-buffered LDS; BOTH tiles are
// [64 rows][128B] read as ds_read_b128 with the validated byte^=(row&7)<<4
// swizzle (r6 post-mortem: V's b64 reads from 64B rows were a structural
// 4-way conflict -> 25M conflict cycles; interleaved global V^T makes the PV
// fragment one 16B read, identical pattern to K). Swizzle applied on the
// per-lane GLOBAL source address (linear LDS dest, rule #21) and re-applied
// on the read side.
// Swapped QK^T: s = mfma(K,Q) puts P[j=16t+4q+r][q-col=l16] in registers; PV
// pa packing follows the interleaved k->j bijection, so P feeds PV straight
// from registers. Scores pre-scaled by 0.125*log2e -> bare v_exp2. P~
// UNNORMALIZED; row-sum L reduced with 2 shuffles; ctx written from regs.
// ---------------------------------------------------------------------------
__global__ __launch_bounds__(256)
void attn_ctx(const bf16* __restrict__ Q, const bf16* __restrict__ K,
              const bf16* __restrict__ Vt, float* __restrict__ Li,
              bf16* __restrict__ ctxOut)
{
    // 1024 blocks; bid%8 = XCD; each XCD gets 128 consecutive semantic idx
    // = 4 full (h,b) groups -> K/V (512KB each) L2-resident per XCD.
    const int bid = blockIdx.x;
    const int l   = (bid & 7) * 128 + (bid >> 3);
    const int q0  = (l & 31) * 64;
    const int h   = (l >> 5) & 15;
    const int b   = l >> 9;

    const int tid = threadIdx.x;
    const int wv = tid >> 6, lane = tid & 63, quad = lane >> 4, l16 = lane & 15;

    __shared__ bf16 Kl[2][4096];   // [buf][64 j][64 dk]  128B rows, swizzled
    __shared__ bf16 Vl[2][4096];   // [buf][64 d][64 pos] 128B rows, swizzled

    const size_t hb = (size_t)(b * H_ + h) * S_;
    const int qw = q0 + wv * 16;   // this wave's 16 q-rows

    bf16x8 qf0, qf1;
    {
        const bf16* qrow = Q + (hb + qw + l16) * DK_;
        qf0 = ld8(qrow + quad*8);
        qf1 = ld8(qrow + 32 + quad*8);
    }
    const char* Kbc = (const char*)(K  + hb * DK_);
    const char* Vbc = (const char*)(Vt + hb * DK_);  // row d at +d*S*2B

    f32x4 cacc[4];      // [db]  C[dk = db*16+quad*4+r][q = l16]
#pragma unroll
    for (int db = 0; db < 4; ++db) cacc[db] = f32x4{0.f,0.f,0.f,0.f};
    float lsum = 0.f;

    // staging constants: each wave fills rows wv*16..+16 of both tiles via
    // 2 calls x 8 rows (64 lanes x 16B = 1024B). lane -> row +(lane>>3),
    // 16B-unit (lane&7); src unit XOR'd with row&7 (= lane>>3).
    const int rbK  = wv * 16;
    const int rlan = lane >> 3;
    const int off  = (((lane & 7) ^ rlan) << 4);

#define STAGE(jc, buf)                                                        \
    do {                                                                      \
        const size_t jb = (size_t)(jc) * 64;                                  \
        g2l16(Kbc + (jb + rbK + rlan) * 128 + off,      &Kl[buf][rbK*64]);    \
        g2l16(Kbc + (jb + rbK + 8 + rlan) * 128 + off,  &Kl[buf][(rbK+8)*64]);\
        g2l16(Vbc + (size_t)(rbK + rlan) * (S_*2) + jb*2 + off,               \
              &Vl[buf][rbK*64]);                                              \
        g2l16(Vbc + (size_t)(rbK + 8 + rlan) * (S_*2) + jb*2 + off,           \
              &Vl[buf][(rbK+8)*64]);                                          \
    } while (0)

    STAGE(0, 0);
    __syncthreads();   // drains vmcnt(0): buf0 ready

    int cur = 0;
    const int sw = (l16 & 7) << 4;   // read-side XOR key (row&7 == l16&7)
    for (int jc = 0; jc < 32; ++jc) {
        STAGE((jc + 1) & 31, cur ^ 1);   // async; drained at the barrier

        const char* kb = (const char*)&Kl[cur][0];
        const char* vb = (const char*)&Vl[cur][0];

        // QK^T: 4 j-tiles of 16
        f32x4 sc[4];
#pragma unroll
        for (int t = 0; t < 4; ++t) {
            const char* kr = kb + (t*16 + l16) * 128;
            bf16x8 ka = *(const bf16x8*)(kr + ((quad*16) ^ sw));
            bf16x8 kbv = *(const bf16x8*)(kr + ((64 + quad*16) ^ sw));
            f32x4 z = {0.f,0.f,0.f,0.f};
            z = __builtin_amdgcn_mfma_f32_16x16x32_bf16(ka, qf0, z, 0, 0, 0);
            sc[t] = __builtin_amdgcn_mfma_f32_16x16x32_bf16(kbv, qf1, z, 0, 0, 0);
        }

        float ex[4][4];
#pragma unroll
        for (int t = 0; t < 4; ++t)
#pragma unroll
            for (int r = 0; r < 4; ++r)
                ex[t][r] = __builtin_amdgcn_exp2f(fminf(sc[t][r], 86.f));
#pragma unroll
        for (int t = 0; t < 4; ++t)
            lsum += (ex[t][0] + ex[t][1]) + (ex[t][2] + ex[t][3]);

        // pa packing for the interleaved V layout: pa_kc[2r+u] = P[j =
        // 32kc + 16u + 4quad + r]  (tile t = 2kc+u)
        bf16x8 pa0, pa1;
#pragma unroll
        for (int r = 0; r < 4; ++r) {
            pa0[2*r]   = (bf16)ex[0][r];
            pa0[2*r+1] = (bf16)ex[1][r];
            pa1[2*r]   = (bf16)ex[2][r];
            pa1[2*r+1] = (bf16)ex[3][r];
        }

        // PV: one b128 V read per (db, kc)
#pragma unroll
        for (int db = 0; db < 4; ++db) {
            const char* vr = vb + (db*16 + l16) * 128;
            bf16x8 va0 = *(const bf16x8*)(vr + ((quad*16) ^ sw));
            bf16x8 va1 = *(const bf16x8*)(vr + ((64 + quad*16) ^ sw));
            cacc[db] = __builtin_amdgcn_mfma_f32_16x16x32_bf16(
                va0, pa0, cacc[db], 0, 0, 0);
            cacc[db] = __builtin_amdgcn_mfma_f32_16x16x32_bf16(
                va1, pa1, cacc[db], 0, 0, 0);
        }

        __syncthreads();   // drains stage vmcnt + all waves done with cur
        cur ^= 1;
    }
#undef STAGE

    // L reduce across quads (lanes sharing l16): all lanes end with their row
    lsum += __shfl_xor(lsum, 16);
    lsum += __shfl_xor(lsum, 32);
    const float linv = 1.0f / fmaxf(lsum, 1e-30f);
    if (lane < 16) Li[hb + qw + lane] = lsum;

    // normalize + write straight from registers (8B stores, dk contiguous)
#pragma unroll
    for (int db = 0; db < 4; ++db) {
        bf16x4 pk;
#pragma unroll
        for (int r = 0; r < 4; ++r) pk[r] = (bf16)(cacc[db][r] * linv);
        *(bf16x4*)(ctxOut + (hb + qw + l16) * DK_ + db*16 + quad*4) = pk;
    }
}

// ---------------------------------------------------------------------------
// Head-mean attention weights. Round-7 post-mortem: at 512 blocks the kernel
// was GRID-LIMITED (2 blocks/CU = 25% occupancy ceiling, measured 19%;
// MfmaUtil 8.9, VALUBusy 28.8 -- latency-bound with 2 waves/SIMD). Now
// 1024 blocks: q-extent halved to 32 rows (asum 64->32 regs, qf 32->16),
// 4 blocks/CU = 16 waves/CU ceiling. Natural register allocation (no
// launch_bounds cap -- round-4 lesson).
// XCD swizzle: each XCD owns one 256-j chunk (K for all h,b = 1MB,
// L2-resident); Q streams. Swapped QK^T: lane holds 4 CONSECUTIVE j for its
// q -> f32x4 stores; linv hoisted per (h,q) with 1/H folded in; bare exp2
// (scale folded into Q projection).
// ---------------------------------------------------------------------------
__global__ __launch_bounds__(256)
void attn_weights(const bf16* __restrict__ Q, const bf16* __restrict__ K,
                  const float* __restrict__ Li, float* __restrict__ attnOut)
{
    // 1024 blocks: l = q-tile32 (64) x b (2) x j-chunk256 (8); each XCD gets
    // 128 consecutive l = one j-chunk, all q, both b. Bijective.
    const int bid = blockIdx.x;
    const int l   = (bid & 7) * 128 + (bid >> 3);
    const int q0  = (l & 63) * 32;
    const int b   = (l >> 6) & 1;
    const int j0  = (l >> 7) * 256;

    const int tid = threadIdx.x;
    const int wv = tid >> 6, lane = tid & 63, quad = lane >> 4, l16 = lane & 15;

    __shared__ float linv[H_][32];
#pragma unroll
    for (int i = 0; i < 2; ++i) {
        int idx = tid * 2 + i;
        int hh = idx >> 5, row = idx & 31;
        linv[hh][row] = (1.0f / H_) /
            fmaxf(Li[(size_t)(b * H_ + hh) * S_ + q0 + row], 1e-30f);
    }
    __syncthreads();

    f32x4 asum[2][4];
#pragma unroll
    for (int qt = 0; qt < 2; ++qt)
#pragma unroll
        for (int t = 0; t < 4; ++t) asum[qt][t] = f32x4{0.f,0.f,0.f,0.f};

    for (int h = 0; h < H_; ++h) {
        const size_t hb = (size_t)(b * H_ + h) * S_;
        bf16x8 qf[2][2];
        float lv[2];
#pragma unroll
        for (int qt = 0; qt < 2; ++qt) {
            const bf16* qrow = Q + (hb + q0 + qt*16 + l16) * DK_;
            qf[qt][0] = ld8(qrow + quad*8);
            qf[qt][1] = ld8(qrow + 32 + quad*8);
            lv[qt] = linv[h][qt*16 + l16];
        }
        const bf16* Kb = K + hb * DK_;
#pragma unroll
        for (int t = 0; t < 4; ++t) {
            const int jl = j0 + wv*64 + t*16;
            const bf16* krow = Kb + (size_t)(jl + l16) * DK_;
            bf16x8 kfa = ld8(krow + quad*8), kfb = ld8(krow + 32 + quad*8);
#pragma unroll
            for (int qt = 0; qt < 2; ++qt) {
                f32x4 z = {0.f,0.f,0.f,0.f};
                z = __builtin_amdgcn_mfma_f32_16x16x32_bf16(kfa, qf[qt][0], z, 0, 0, 0);
                f32x4 s = __builtin_amdgcn_mfma_f32_16x16x32_bf16(kfb, qf[qt][1], z, 0, 0, 0);
#pragma unroll
                for (int r = 0; r < 4; ++r)
                    asum[qt][t][r] += __builtin_amdgcn_exp2f(fminf(s[r], 86.f)) * lv[qt];
            }
        }
    }
#pragma unroll
    for (int qt = 0; qt < 2; ++qt)
#pragma unroll
        for (int t = 0; t < 4; ++t)
            *(f32x4*)(attnOut + ((size_t)b * S_ + q0 + qt*16 + l16) * S_
                      + j0 + wv*64 + t*16 + quad*4) = asum[qt][t];
}

// ---------------------------------------------------------------------------
extern "C" void kernel_launch(void* const* d_in, const int* in_sizes, int n_in,
                              void* d_out, int out_size, void* d_ws, size_t ws_size,
                              hipStream_t stream)
{
    (void)in_sizes; (void)n_in; (void)out_size; (void)ws_size;

    const float* query = (const float*)d_in[0];
    const float* key_t = (const float*)d_in[1];
    const float* value = (const float*)d_in[2];
    const float* Wq = (const float*)d_in[3];
    const float* bq = (const float*)d_in[4];
    const float* Wk = (const float*)d_in[5];
    const float* bk = (const float*)d_in[6];
    const float* Wv = (const float*)d_in[7];
    const float* bv = (const float*)d_in[8];
    const float* Wo = (const float*)d_in[9];
    const float* bo = (const float*)d_in[10];

    float* out     = (float*)d_out;                  // (B,S,D) fp32
    float* attnOut = out + (size_t)B_ * S_ * D_;     // (B,S,S) fp32

    const size_t nX = (size_t)B_ * S_ * D_;
    const size_t nW = (size_t)D_ * D_;

    // d_out doubles as scratch for bf16 X-converts (dead before overwrites)
    bf16* Xqb = (bf16*)d_out;
    bf16* Xkb = Xqb + nX;
    bf16* Xvb = Xkb + nX;

    // ws: Qh,Kh,VtH (25.2MB) + Wob (2.1MB) + Li (0.26MB) + [Wqb/Wkb/Wvb
    // overlaid by CtxH (8.4MB) -- W converts are dead before attn_ctx runs].
    bf16* Qh  = (bf16*)d_ws;
    bf16* Kh  = Qh + nX;
    bf16* VtH = Kh + nX;                 // V^T (B,H,DK,S), pair-interleaved
    bf16* Wob = VtH + nX;
    float* Li = (float*)(Wob + nW);
    bf16* Wqb = (bf16*)(Li + (size_t)B_ * H_ * S_);
    bf16* Wkb = Wqb + nW;
    bf16* Wvb = Wkb + nW;
    bf16* CtxH = Wqb;                                // overlays dead W converts

    cvt_all<<<8192, 256, 0, stream>>>(query, key_t, value, Wq, Wk, Wv, Wo,
                                      Xqb, Xkb, Xvb, Wqb, Wkb, Wvb, Wob);
    dim3 gg(M_/128, D_/128);
    // Q pre-scaled by 1/sqrt(DK) * log2(e): softmax scale + exp->exp2 fold
    gemm128<<<gg, 256, 0, stream>>>(Xqb, Wqb, bq, Qh, 0, 0, 0.18033688011112042f);
    gemm128<<<gg, 256, 0, stream>>>(Xkb, Wkb, bk, Kh, 0, 0, 1.0f);
    gemm128<<<gg, 256, 0, stream>>>(Xvb, Wvb, bv, VtH, 0, 2, 1.0f);   // V^T
    attn_ctx    <<<1024, 256, 0, stream>>>(Qh, Kh, VtH, Li, CtxH);
    attn_weights<<<1024, 256, 0, stream>>>(Qh, Kh, Li, attnOut);
    gemm128<<<gg, 256, 0, stream>>>(CtxH, Wob, bo, out, 1, 1, 1.0f);
}

// Round 9
// 363.778 us; speedup vs baseline: 1.0340x; 1.0340x over previous
//
#include <hip/hip_runtime.h>

// Problem constants (B,S,D,H from reference)
#define B_ 2
#define S_ 2048
#define D_ 1024
#define H_ 16
#define DK_ 64
#define M_ (B_ * S_)      // 4096 rows in the projection GEMMs

typedef __bf16 bf16;
typedef __attribute__((ext_vector_type(8))) __bf16 bf16x8;
typedef __attribute__((ext_vector_type(4))) __bf16 bf16x4;
typedef __attribute__((ext_vector_type(4))) float f32x4;

static __device__ __forceinline__ bf16x8 ld8(const bf16* p) {
    return *(const bf16x8*)p;   // 16B aligned by construction
}

// Async global->LDS, 16B per lane. LDS dest = wave-uniform base + lane*16
// (linear); global src is per-lane (carries the swizzle).
static __device__ __forceinline__ void g2l16(const void* g, void* l) {
    __builtin_amdgcn_global_load_lds(
        (const __attribute__((address_space(1))) unsigned int*)g,
        (__attribute__((address_space(3))) unsigned int*)l, 16, 0, 0);
}

// ---------------------------------------------------------------------------
// Elementwise fp32 -> bf16 for the 3 X inputs (into d_out scratch) and the
// 4 weight matrices (into ws). Block mapping: 3*2048 X-blocks + 4*512 W-blocks.
// ---------------------------------------------------------------------------
__global__ __launch_bounds__(256)
void cvt_all(const float* __restrict__ xq, const float* __restrict__ xk,
             const float* __restrict__ xv, const float* __restrict__ wq,
             const float* __restrict__ wk, const float* __restrict__ wv,
             const float* __restrict__ wo, bf16* __restrict__ xqo,
             bf16* __restrict__ xko, bf16* __restrict__ xvo,
             bf16* __restrict__ wqo, bf16* __restrict__ wko,
             bf16* __restrict__ wvo, bf16* __restrict__ woo)
{
    const int bx = blockIdx.x;
    const float* s; bf16* d; size_t base;
    if (bx < 6144) {
        int a = bx >> 11;
        s = (a == 0) ? xq : (a == 1) ? xk : xv;
        d = (a == 0) ? xqo : (a == 1) ? xko : xvo;
        base = (size_t)(bx & 2047) * 2048;
    } else {
        int a = (bx - 6144) >> 9;
        s = (a == 0) ? wq : (a == 1) ? wk : (a == 2) ? wv : wo;
        d = (a == 0) ? wqo : (a == 1) ? wko : (a == 2) ? wvo : woo;
        base = (size_t)((bx - 6144) & 511) * 2048;
    }
    size_t i = base + (size_t)threadIdx.x * 8;
    f32x4 a4 = *(const f32x4*)(s + i);
    f32x4 b4 = *(const f32x4*)(s + i + 4);
    bf16x8 r;
    r[0]=(bf16)a4[0]; r[1]=(bf16)a4[1]; r[2]=(bf16)a4[2]; r[3]=(bf16)a4[3];
    r[4]=(bf16)b4[0]; r[5]=(bf16)b4[1]; r[6]=(bf16)b4[2]; r[7]=(bf16)b4[3];
    *(bf16x8*)(d + i) = r;
}

// ---------------------------------------------------------------------------
// 128x128-tile bf16 GEMM, LDS-staged, 2-barrier K-loop.
// out_mode: 0 = bf16 head-split (B,H,S,DK);  1 = fp32 flat (M,N);
//           2 = bf16 V^T head-split (B,H,DK,S) with PAIR-INTERLEAVED tokens:
//               within each 32-token block, element order is
//               (j0,j0+16,j0+1,j0+17,...,j0+15,j0+31)  [pos=2*(j&15)+(j>>4)].
//               This makes attn_ctx's PV fragment one contiguous 16B read.
// a_headsplit: A element (m,k) at ((b*H+h)*S+s)*DK+dk (ctx layout).
// scale: applied after bias. Q gemm folds 0.125*log2(e) (softmax 1/sqrt(DK)
//        plus the exp->exp2 conversion factor).
// ---------------------------------------------------------------------------
__global__ __launch_bounds__(256)
void gemm128(const bf16* __restrict__ A, const bf16* __restrict__ W,
             const float* __restrict__ bias, void* __restrict__ out,
             int a_headsplit, int out_mode, float scale)
{
    const int m0 = blockIdx.x * 128, n0 = blockIdx.y * 128;
    const int tid = threadIdx.x;
    const int wv = tid >> 6, lane = tid & 63, quad = lane >> 4, l16 = lane & 15;
    const int wr = (wv >> 1) * 64, wc = (wv & 1) * 64;

    __shared__ bf16 As[128 * 32];
    __shared__ bf16 Bs[128 * 32];

    f32x4 acc[4][4];
#pragma unroll
    for (int i = 0; i < 4; ++i)
#pragma unroll
        for (int j = 0; j < 4; ++j) acc[i][j] = f32x4{0.f, 0.f, 0.f, 0.f};

    const int srow = tid >> 2;
    const int scol = (tid & 3) * 8;

    for (int k0 = 0; k0 < D_; k0 += 32) {
        bf16x8 av[2], bw[2];
#pragma unroll
        for (int c = 0; c < 2; ++c) {
            const int row = c * 64 + srow;
            const int k   = k0 + scol;
            const bf16* ap;
            if (a_headsplit) {
                int m = m0 + row, bb = m >> 11, ss = m & (S_ - 1);
                int hh = k >> 6, dd = k & (DK_ - 1);
                ap = A + (((size_t)(bb * H_ + hh) * S_ + ss) * DK_ + dd);
            } else {
                ap = A + (size_t)(m0 + row) * D_ + k;
            }
            av[c] = ld8(ap);
            bw[c] = ld8(W + (size_t)(n0 + row) * D_ + k);
        }
        __syncthreads();
#pragma unroll
        for (int c = 0; c < 2; ++c) {
            const int e = c * 2048 + tid * 8;
            *(bf16x8*)(As + e) = av[c];
            *(bf16x8*)(Bs + e) = bw[c];
        }
        __syncthreads();

        bf16x8 af[4], bfr[4];
#pragma unroll
        for (int i = 0; i < 4; ++i)
            af[i] = *(const bf16x8*)(As + (wr + i*16 + l16) * 32 + quad * 8);
#pragma unroll
        for (int j = 0; j < 4; ++j)
            bfr[j] = *(const bf16x8*)(Bs + (wc + j*16 + l16) * 32 + quad * 8);
#pragma unroll
        for (int i = 0; i < 4; ++i)
#pragma unroll
            for (int j = 0; j < 4; ++j)
                acc[i][j] = __builtin_amdgcn_mfma_f32_16x16x32_bf16(
                    af[i], bfr[j], acc[i][j], 0, 0, 0);
    }

    if (out_mode == 2) {
        // V^T pair-interleaved: i-tiles 2ip (tokens s..s+15 region) and 2ip+1
        // (s+16..s+31) share a 32-token block; interleaving their r-elements
        // gives one contiguous 16B store at pos-base 2*(s&15).
#pragma unroll
        for (int j = 0; j < 4; ++j) {
            const int nn = n0 + wc + j*16 + l16;      // d index
            const float bvv = bias[nn];
            int hh = nn >> 6, dd = nn & (DK_ - 1);
#pragma unroll
            for (int ip = 0; ip < 2; ++ip) {
                const int mlo = m0 + wr + 32*ip + quad*4;   // token of (2ip, r=0)
                int bb = mlo >> 11, sl = mlo & (S_ - 1);
                int g0 = (sl & ~31) + ((sl & 15) << 1);
                bf16x8 pk;
#pragma unroll
                for (int r = 0; r < 4; ++r) {
                    pk[2*r]   = (bf16)((acc[2*ip  ][j][r] + bvv) * scale);
                    pk[2*r+1] = (bf16)((acc[2*ip+1][j][r] + bvv) * scale);
                }
                *(bf16x8*)((bf16*)out +
                    ((size_t)(bb * H_ + hh) * DK_ + dd) * S_ + g0) = pk;
            }
        }
    } else {
#pragma unroll
        for (int i = 0; i < 4; ++i)
#pragma unroll
            for (int j = 0; j < 4; ++j) {
                const int nn = n0 + wc + j*16 + l16;
                const float bvv = bias[nn];
                const int mm0 = m0 + wr + i*16 + quad*4;   // 4-aligned, same b
#pragma unroll
                for (int r = 0; r < 4; ++r) {
                    const int mm = mm0 + r;
                    float v = (acc[i][j][r] + bvv) * scale;
                    if (out_mode == 1) {
                        ((float*)out)[(size_t)mm * D_ + nn] = v;
                    } else {
                        int bb = mm >> 11, ss = mm & (S_ - 1);
                        int hh = nn >> 6, dd = nn & (DK_ - 1);
                        ((bf16*)out)[((size_t)(bb * H_ + hh) * S_ + ss) * DK_ + dd] = (bf16)v;
                    }
                }
            }
    }
}

// ---------------------------------------------------------------------------
// Context + softmax denominators, fused.
// Block = 64 q-rows, one (h,b); 4 waves; each wave owns 16 q-rows over the
// full j-range (no cross-wave reduce). K and interleaved-V^T staged in 64-j
// chunks via global_load_lds into double-buffered LDS; BOTH tiles are
// [64 rows][128B] read as ds_read_b128 with the validated byte^=(row&7)<<4
// swizzle. Swizzle applied on the per-lane GLOBAL source address (linear LDS
// dest, rule #21) and re-applied on the read side.
// Swapped QK^T: s = mfma(K,Q) puts P[j=16t+4q+r][q-col=l16] in registers; PV
// pa packing follows the interleaved k->j bijection, so P feeds PV straight
// from registers. Scores pre-scaled by 0.125*log2e -> bare v_exp2. P~
// UNNORMALIZED; row-sum L reduced with 2 shuffles; ctx written from regs.
// ---------------------------------------------------------------------------
__global__ __launch_bounds__(256)
void attn_ctx(const bf16* __restrict__ Q, const bf16* __restrict__ K,
              const bf16* __restrict__ Vt, float* __restrict__ Li,
              bf16* __restrict__ ctxOut)
{
    // 1024 blocks; bid%8 = XCD; each XCD gets 128 consecutive semantic idx
    // = 4 full (h,b) groups -> K/V (512KB each) L2-resident per XCD.
    const int bid = blockIdx.x;
    const int l   = (bid & 7) * 128 + (bid >> 3);
    const int q0  = (l & 31) * 64;
    const int h   = (l >> 5) & 15;
    const int b   = l >> 9;

    const int tid = threadIdx.x;
    const int wv = tid >> 6, lane = tid & 63, quad = lane >> 4, l16 = lane & 15;

    __shared__ bf16 Kl[2][4096];   // [buf][64 j][64 dk]  128B rows, swizzled
    __shared__ bf16 Vl[2][4096];   // [buf][64 d][64 pos] 128B rows, swizzled

    const size_t hb = (size_t)(b * H_ + h) * S_;
    const int qw = q0 + wv * 16;   // this wave's 16 q-rows

    bf16x8 qf0, qf1;
    {
        const bf16* qrow = Q + (hb + qw + l16) * DK_;
        qf0 = ld8(qrow + quad*8);
        qf1 = ld8(qrow + 32 + quad*8);
    }
    const char* Kbc = (const char*)(K  + hb * DK_);
    const char* Vbc = (const char*)(Vt + hb * DK_);  // row d at +d*S*2B

    f32x4 cacc[4];      // [db]  C[dk = db*16+quad*4+r][q = l16]
#pragma unroll
    for (int db = 0; db < 4; ++db) cacc[db] = f32x4{0.f,0.f,0.f,0.f};
    float lsum = 0.f;

    // staging constants: each wave fills rows wv*16..+16 of both tiles via
    // 2 calls x 8 rows (64 lanes x 16B = 1024B). lane -> row +(lane>>3),
    // 16B-unit (lane&7); src unit XOR'd with row&7 (= lane>>3).
    const int rbK  = wv * 16;
    const int rlan = lane >> 3;
    const int off  = (((lane & 7) ^ rlan) << 4);

#define STAGE(jc, buf)                                                        \
    do {                                                                      \
        const size_t jb = (size_t)(jc) * 64;                                  \
        g2l16(Kbc + (jb + rbK + rlan) * 128 + off,      &Kl[buf][rbK*64]);    \
        g2l16(Kbc + (jb + rbK + 8 + rlan) * 128 + off,  &Kl[buf][(rbK+8)*64]);\
        g2l16(Vbc + (size_t)(rbK + rlan) * (S_*2) + jb*2 + off,               \
              &Vl[buf][rbK*64]);                                              \
        g2l16(Vbc + (size_t)(rbK + 8 + rlan) * (S_*2) + jb*2 + off,           \
              &Vl[buf][(rbK+8)*64]);                                          \
    } while (0)

    STAGE(0, 0);
    __syncthreads();   // drains vmcnt(0): buf0 ready

    int cur = 0;
    const int sw = (l16 & 7) << 4;   // read-side XOR key (row&7 == l16&7)
    for (int jc = 0; jc < 32; ++jc) {
        STAGE((jc + 1) & 31, cur ^ 1);   // async; drained at the barrier

        const char* kb = (const char*)&Kl[cur][0];
        const char* vb = (const char*)&Vl[cur][0];

        // QK^T: 4 j-tiles of 16
        f32x4 sc[4];
#pragma unroll
        for (int t = 0; t < 4; ++t) {
            const char* kr = kb + (t*16 + l16) * 128;
            bf16x8 ka = *(const bf16x8*)(kr + ((quad*16) ^ sw));
            bf16x8 kbv = *(const bf16x8*)(kr + ((64 + quad*16) ^ sw));
            f32x4 z = {0.f,0.f,0.f,0.f};
            z = __builtin_amdgcn_mfma_f32_16x16x32_bf16(ka, qf0, z, 0, 0, 0);
            sc[t] = __builtin_amdgcn_mfma_f32_16x16x32_bf16(kbv, qf1, z, 0, 0, 0);
        }

        float ex[4][4];
#pragma unroll
        for (int t = 0; t < 4; ++t)
#pragma unroll
            for (int r = 0; r < 4; ++r)
                ex[t][r] = __builtin_amdgcn_exp2f(fminf(sc[t][r], 86.f));
#pragma unroll
        for (int t = 0; t < 4; ++t)
            lsum += (ex[t][0] + ex[t][1]) + (ex[t][2] + ex[t][3]);

        // pa packing for the interleaved V layout: pa_kc[2r+u] = P[j =
        // 32kc + 16u + 4quad + r]  (tile t = 2kc+u)
        bf16x8 pa0, pa1;
#pragma unroll
        for (int r = 0; r < 4; ++r) {
            pa0[2*r]   = (bf16)ex[0][r];
            pa0[2*r+1] = (bf16)ex[1][r];
            pa1[2*r]   = (bf16)ex[2][r];
            pa1[2*r+1] = (bf16)ex[3][r];
        }

        // PV: one b128 V read per (db, kc)
#pragma unroll
        for (int db = 0; db < 4; ++db) {
            const char* vr = vb + (db*16 + l16) * 128;
            bf16x8 va0 = *(const bf16x8*)(vr + ((quad*16) ^ sw));
            bf16x8 va1 = *(const bf16x8*)(vr + ((64 + quad*16) ^ sw));
            cacc[db] = __builtin_amdgcn_mfma_f32_16x16x32_bf16(
                va0, pa0, cacc[db], 0, 0, 0);
            cacc[db] = __builtin_amdgcn_mfma_f32_16x16x32_bf16(
                va1, pa1, cacc[db], 0, 0, 0);
        }

        __syncthreads();   // drains stage vmcnt + all waves done with cur
        cur ^= 1;
    }
#undef STAGE

    // L reduce across quads (lanes sharing l16): all lanes end with their row
    lsum += __shfl_xor(lsum, 16);
    lsum += __shfl_xor(lsum, 32);
    const float linv = 1.0f / fmaxf(lsum, 1e-30f);
    if (lane < 16) Li[hb + qw + lane] = lsum;

    // normalize + write straight from registers (8B stores, dk contiguous)
#pragma unroll
    for (int db = 0; db < 4; ++db) {
        bf16x4 pk;
#pragma unroll
        for (int r = 0; r < 4; ++r) pk[r] = (bf16)(cacc[db][r] * linv);
        *(bf16x4*)(ctxOut + (hb + qw + l16) * DK_ + db*16 + quad*4) = pk;
    }
}

// ---------------------------------------------------------------------------
// Head-mean attention weights.
// r7: 512 blocks x 4 waves = 2 blocks/CU = 8 waves/CU ceiling -> 19% occ,
//     latency-bound (72.8us). r8: doubling BLOCKS halved q-extent -> 2x K L2
//     traffic + half Q amortization -> 102us. Lesson: add waves WITHIN the
//     block (operands shared), not blocks.
// Now: same 512-block geometry (q-tile64 x b x j-chunk256 -- K rows read
// once per block, traffic identical to r7) but 8 WAVES (512 threads), each
// wave owning 32 j (2 j-tiles) x all 64 q x all 16 h. 16 waves/CU ceiling;
// only the L1-hot Q reloads double. Natural reg allocation (no cap).
// XCD swizzle: each XCD owns one j-chunk (K for all h,b = 1MB, L2-resident).
// Swapped QK^T: lane holds 4 CONSECUTIVE j for its q -> f32x4 stores; linv
// hoisted per (h,q) with 1/H folded in; bare exp2 (scale folded into Q).
// ---------------------------------------------------------------------------
__global__ __launch_bounds__(512)
void attn_weights(const bf16* __restrict__ Q, const bf16* __restrict__ K,
                  const float* __restrict__ Li, float* __restrict__ attnOut)
{
    // 512 blocks: l = q-tile (32) x b (2) x j-chunk (8); each XCD gets 64
    // consecutive l = one j-chunk, both b. Bijective.
    const int bid = blockIdx.x;
    const int l   = (bid & 7) * 64 + (bid >> 3);
    const int q0  = (l & 31) * 64;
    const int b   = (l >> 5) & 1;
    const int j0  = (l >> 6) * 256;

    const int tid = threadIdx.x;
    const int wv = tid >> 6, lane = tid & 63, quad = lane >> 4, l16 = lane & 15;

    __shared__ float linv[H_][64];
    {
        int idx = tid * 2;
        int hh = idx >> 6, row = idx & 63;
        float v0 = (1.0f / H_) /
            fmaxf(Li[(size_t)(b * H_ + hh) * S_ + q0 + row], 1e-30f);
        float v1 = (1.0f / H_) /
            fmaxf(Li[(size_t)(b * H_ + hh) * S_ + q0 + row + 1], 1e-30f);
        linv[hh][row] = v0;
        linv[hh][row + 1] = v1;
    }
    __syncthreads();

    f32x4 asum[4][2];
#pragma unroll
    for (int qt = 0; qt < 4; ++qt)
#pragma unroll
        for (int t = 0; t < 2; ++t) asum[qt][t] = f32x4{0.f,0.f,0.f,0.f};

    for (int h = 0; h < H_; ++h) {
        const size_t hb = (size_t)(b * H_ + h) * S_;
        bf16x8 qf[4][2];
        float lv[4];
#pragma unroll
        for (int qt = 0; qt < 4; ++qt) {
            const bf16* qrow = Q + (hb + q0 + qt*16 + l16) * DK_;
            qf[qt][0] = ld8(qrow + quad*8);
            qf[qt][1] = ld8(qrow + 32 + quad*8);
            lv[qt] = linv[h][qt*16 + l16];
        }
        const bf16* Kb = K + hb * DK_;
#pragma unroll
        for (int t = 0; t < 2; ++t) {
            const int jl = j0 + wv*32 + t*16;
            const bf16* krow = Kb + (size_t)(jl + l16) * DK_;
            bf16x8 kfa = ld8(krow + quad*8), kfb = ld8(krow + 32 + quad*8);
#pragma unroll
            for (int qt = 0; qt < 4; ++qt) {
                f32x4 z = {0.f,0.f,0.f,0.f};
                z = __builtin_amdgcn_mfma_f32_16x16x32_bf16(kfa, qf[qt][0], z, 0, 0, 0);
                f32x4 s = __builtin_amdgcn_mfma_f32_16x16x32_bf16(kfb, qf[qt][1], z, 0, 0, 0);
#pragma unroll
                for (int r = 0; r < 4; ++r)
                    asum[qt][t][r] += __builtin_amdgcn_exp2f(fminf(s[r], 86.f)) * lv[qt];
            }
        }
    }
#pragma unroll
    for (int qt = 0; qt < 4; ++qt)
#pragma unroll
        for (int t = 0; t < 2; ++t)
            *(f32x4*)(attnOut + ((size_t)b * S_ + q0 + qt*16 + l16) * S_
                      + j0 + wv*32 + t*16 + quad*4) = asum[qt][t];
}

// ---------------------------------------------------------------------------
extern "C" void kernel_launch(void* const* d_in, const int* in_sizes, int n_in,
                              void* d_out, int out_size, void* d_ws, size_t ws_size,
                              hipStream_t stream)
{
    (void)in_sizes; (void)n_in; (void)out_size; (void)ws_size;

    const float* query = (const float*)d_in[0];
    const float* key_t = (const float*)d_in[1];
    const float* value = (const float*)d_in[2];
    const float* Wq = (const float*)d_in[3];
    const float* bq = (const float*)d_in[4];
    const float* Wk = (const float*)d_in[5];
    const float* bk = (const float*)d_in[6];
    const float* Wv = (const float*)d_in[7];
    const float* bv = (const float*)d_in[8];
    const float* Wo = (const float*)d_in[9];
    const float* bo = (const float*)d_in[10];

    float* out     = (float*)d_out;                  // (B,S,D) fp32
    float* attnOut = out + (size_t)B_ * S_ * D_;     // (B,S,S) fp32

    const size_t nX = (size_t)B_ * S_ * D_;
    const size_t nW = (size_t)D_ * D_;

    // d_out doubles as scratch for bf16 X-converts (dead before overwrites)
    bf16* Xqb = (bf16*)d_out;
    bf16* Xkb = Xqb + nX;
    bf16* Xvb = Xkb + nX;

    // ws: Qh,Kh,VtH (25.2MB) + Wob (2.1MB) + Li (0.26MB) + [Wqb/Wkb/Wvb
    // overlaid by CtxH (8.4MB) -- W converts are dead before attn_ctx runs].
    bf16* Qh  = (bf16*)d_ws;
    bf16* Kh  = Qh + nX;
    bf16* VtH = Kh + nX;                 // V^T (B,H,DK,S), pair-interleaved
    bf16* Wob = VtH + nX;
    float* Li = (float*)(Wob + nW);
    bf16* Wqb = (bf16*)(Li + (size_t)B_ * H_ * S_);
    bf16* Wkb = Wqb + nW;
    bf16* Wvb = Wkb + nW;
    bf16* CtxH = Wqb;                                // overlays dead W converts

    cvt_all<<<8192, 256, 0, stream>>>(query, key_t, value, Wq, Wk, Wv, Wo,
                                      Xqb, Xkb, Xvb, Wqb, Wkb, Wvb, Wob);
    dim3 gg(M_/128, D_/128);
    // Q pre-scaled by 1/sqrt(DK) * log2(e): softmax scale + exp->exp2 fold
    gemm128<<<gg, 256, 0, stream>>>(Xqb, Wqb, bq, Qh, 0, 0, 0.18033688011112042f);
    gemm128<<<gg, 256, 0, stream>>>(Xkb, Wkb, bk, Kh, 0, 0, 1.0f);
    gemm128<<<gg, 256, 0, stream>>>(Xvb, Wvb, bv, VtH, 0, 2, 1.0f);   // V^T
    attn_ctx    <<<1024, 256, 0, stream>>>(Qh, Kh, VtH, Li, CtxH);
    attn_weights<<<512, 512, 0, stream>>>(Qh, Kh, Li, attnOut);
    gemm128<<<gg, 256, 0, stream>>>(CtxH, Wob, bo, out, 1, 1, 1.0f);
}

// Round 10
// 354.873 us; speedup vs baseline: 1.0599x; 1.0251x over previous
//
#include <hip/hip_runtime.h>

// Problem constants (B,S,D,H from reference)
#define B_ 2
#define S_ 2048
#define D_ 1024
#define H_ 16
#define DK_ 64
#define M_ (B_ * S_)      // 4096 rows in the projection GEMMs

typedef __bf16 bf16;
typedef __attribute__((ext_vector_type(8))) __bf16 bf16x8;
typedef __attribute__((ext_vector_type(4))) __bf16 bf16x4;
typedef __attribute__((ext_vector_type(4))) float f32x4;

static __device__ __forceinline__ bf16x8 ld8(const bf16* p) {
    return *(const bf16x8*)p;   // 16B aligned by construction
}

// Async global->LDS, 16B per lane. LDS dest = wave-uniform base + lane*16
// (linear); global src is per-lane (carries the swizzle).
static __device__ __forceinline__ void g2l16(const void* g, void* l) {
    __builtin_amdgcn_global_load_lds(
        (const __attribute__((address_space(1))) unsigned int*)g,
        (__attribute__((address_space(3))) unsigned int*)l, 16, 0, 0);
}

// ---------------------------------------------------------------------------
// Elementwise fp32 -> bf16 for the 3 X inputs (into d_out scratch) and the
// 4 weight matrices (into ws). Block mapping: 3*2048 X-blocks + 4*512 W-blocks.
// ---------------------------------------------------------------------------
__global__ __launch_bounds__(256)
void cvt_all(const float* __restrict__ xq, const float* __restrict__ xk,
             const float* __restrict__ xv, const float* __restrict__ wq,
             const float* __restrict__ wk, const float* __restrict__ wv,
             const float* __restrict__ wo, bf16* __restrict__ xqo,
             bf16* __restrict__ xko, bf16* __restrict__ xvo,
             bf16* __restrict__ wqo, bf16* __restrict__ wko,
             bf16* __restrict__ wvo, bf16* __restrict__ woo)
{
    const int bx = blockIdx.x;
    const float* s; bf16* d; size_t base;
    if (bx < 6144) {
        int a = bx >> 11;
        s = (a == 0) ? xq : (a == 1) ? xk : xv;
        d = (a == 0) ? xqo : (a == 1) ? xko : xvo;
        base = (size_t)(bx & 2047) * 2048;
    } else {
        int a = (bx - 6144) >> 9;
        s = (a == 0) ? wq : (a == 1) ? wk : (a == 2) ? wv : wo;
        d = (a == 0) ? wqo : (a == 1) ? wko : (a == 2) ? wvo : woo;
        base = (size_t)((bx - 6144) & 511) * 2048;
    }
    size_t i = base + (size_t)threadIdx.x * 8;
    f32x4 a4 = *(const f32x4*)(s + i);
    f32x4 b4 = *(const f32x4*)(s + i + 4);
    bf16x8 r;
    r[0]=(bf16)a4[0]; r[1]=(bf16)a4[1]; r[2]=(bf16)a4[2]; r[3]=(bf16)a4[3];
    r[4]=(bf16)b4[0]; r[5]=(bf16)b4[1]; r[6]=(bf16)b4[2]; r[7]=(bf16)b4[3];
    *(bf16x8*)(d + i) = r;
}

// ---------------------------------------------------------------------------
// 128x128-tile bf16 GEMM, LDS-staged, 2-barrier K-loop.
// out_mode: 0 = bf16 head-split (B,H,S,DK);  1 = fp32 flat (M,N);
//           2 = bf16 V^T head-split (B,H,DK,S) with PAIR-INTERLEAVED tokens:
//               within each 32-token block, element order is
//               (j0,j0+16,j0+1,j0+17,...,j0+15,j0+31)  [pos=2*(j&15)+(j>>4)].
//               This makes attn_ctx's PV fragment one contiguous 16B read.
// a_headsplit: A element (m,k) at ((b*H+h)*S+s)*DK+dk (ctx layout).
// scale: applied after bias. Q gemm folds 0.125*log2(e) (softmax 1/sqrt(DK)
//        plus the exp->exp2 conversion factor).
// ---------------------------------------------------------------------------
__global__ __launch_bounds__(256)
void gemm128(const bf16* __restrict__ A, const bf16* __restrict__ W,
             const float* __restrict__ bias, void* __restrict__ out,
             int a_headsplit, int out_mode, float scale)
{
    const int m0 = blockIdx.x * 128, n0 = blockIdx.y * 128;
    const int tid = threadIdx.x;
    const int wv = tid >> 6, lane = tid & 63, quad = lane >> 4, l16 = lane & 15;
    const int wr = (wv >> 1) * 64, wc = (wv & 1) * 64;

    __shared__ bf16 As[128 * 32];
    __shared__ bf16 Bs[128 * 32];

    f32x4 acc[4][4];
#pragma unroll
    for (int i = 0; i < 4; ++i)
#pragma unroll
        for (int j = 0; j < 4; ++j) acc[i][j] = f32x4{0.f, 0.f, 0.f, 0.f};

    const int srow = tid >> 2;
    const int scol = (tid & 3) * 8;

    for (int k0 = 0; k0 < D_; k0 += 32) {
        bf16x8 av[2], bw[2];
#pragma unroll
        for (int c = 0; c < 2; ++c) {
            const int row = c * 64 + srow;
            const int k   = k0 + scol;
            const bf16* ap;
            if (a_headsplit) {
                int m = m0 + row, bb = m >> 11, ss = m & (S_ - 1);
                int hh = k >> 6, dd = k & (DK_ - 1);
                ap = A + (((size_t)(bb * H_ + hh) * S_ + ss) * DK_ + dd);
            } else {
                ap = A + (size_t)(m0 + row) * D_ + k;
            }
            av[c] = ld8(ap);
            bw[c] = ld8(W + (size_t)(n0 + row) * D_ + k);
        }
        __syncthreads();
#pragma unroll
        for (int c = 0; c < 2; ++c) {
            const int e = c * 2048 + tid * 8;
            *(bf16x8*)(As + e) = av[c];
            *(bf16x8*)(Bs + e) = bw[c];
        }
        __syncthreads();

        bf16x8 af[4], bfr[4];
#pragma unroll
        for (int i = 0; i < 4; ++i)
            af[i] = *(const bf16x8*)(As + (wr + i*16 + l16) * 32 + quad * 8);
#pragma unroll
        for (int j = 0; j < 4; ++j)
            bfr[j] = *(const bf16x8*)(Bs + (wc + j*16 + l16) * 32 + quad * 8);
#pragma unroll
        for (int i = 0; i < 4; ++i)
#pragma unroll
            for (int j = 0; j < 4; ++j)
                acc[i][j] = __builtin_amdgcn_mfma_f32_16x16x32_bf16(
                    af[i], bfr[j], acc[i][j], 0, 0, 0);
    }

    if (out_mode == 2) {
        // V^T pair-interleaved: i-tiles 2ip (tokens s..s+15 region) and 2ip+1
        // (s+16..s+31) share a 32-token block; interleaving their r-elements
        // gives one contiguous 16B store at pos-base 2*(s&15).
#pragma unroll
        for (int j = 0; j < 4; ++j) {
            const int nn = n0 + wc + j*16 + l16;      // d index
            const float bvv = bias[nn];
            int hh = nn >> 6, dd = nn & (DK_ - 1);
#pragma unroll
            for (int ip = 0; ip < 2; ++ip) {
                const int mlo = m0 + wr + 32*ip + quad*4;   // token of (2ip, r=0)
                int bb = mlo >> 11, sl = mlo & (S_ - 1);
                int g0 = (sl & ~31) + ((sl & 15) << 1);
                bf16x8 pk;
#pragma unroll
                for (int r = 0; r < 4; ++r) {
                    pk[2*r]   = (bf16)((acc[2*ip  ][j][r] + bvv) * scale);
                    pk[2*r+1] = (bf16)((acc[2*ip+1][j][r] + bvv) * scale);
                }
                *(bf16x8*)((bf16*)out +
                    ((size_t)(bb * H_ + hh) * DK_ + dd) * S_ + g0) = pk;
            }
        }
    } else {
#pragma unroll
        for (int i = 0; i < 4; ++i)
#pragma unroll
            for (int j = 0; j < 4; ++j) {
                const int nn = n0 + wc + j*16 + l16;
                const float bvv = bias[nn];
                const int mm0 = m0 + wr + i*16 + quad*4;   // 4-aligned, same b
#pragma unroll
                for (int r = 0; r < 4; ++r) {
                    const int mm = mm0 + r;
                    float v = (acc[i][j][r] + bvv) * scale;
                    if (out_mode == 1) {
                        ((float*)out)[(size_t)mm * D_ + nn] = v;
                    } else {
                        int bb = mm >> 11, ss = mm & (S_ - 1);
                        int hh = nn >> 6, dd = nn & (DK_ - 1);
                        ((bf16*)out)[((size_t)(bb * H_ + hh) * S_ + ss) * DK_ + dd] = (bf16)v;
                    }
                }
            }
    }
}

// ---------------------------------------------------------------------------
// Context + softmax denominators, fused.
// Block = 64 q-rows, one (h,b); 4 waves; each wave owns 16 q-rows over the
// full j-range (no cross-wave reduce). K and interleaved-V^T staged in 64-j
// chunks via global_load_lds into double-buffered LDS; BOTH tiles are
// [64 rows][128B] read as ds_read_b128 with the validated byte^=(row&7)<<4
// swizzle. Swizzle applied on the per-lane GLOBAL source address (linear LDS
// dest, rule #21) and re-applied on the read side.
// Swapped QK^T: s = mfma(K,Q) puts P[j=16t+4q+r][q-col=l16] in registers; PV
// pa packing follows the interleaved k->j bijection, so P feeds PV straight
// from registers. Scores pre-scaled by 0.125*log2e -> bare v_exp2. P~
// UNNORMALIZED; row-sum L reduced with 2 shuffles; ctx written from regs.
// ---------------------------------------------------------------------------
__global__ __launch_bounds__(256)
void attn_ctx(const bf16* __restrict__ Q, const bf16* __restrict__ K,
              const bf16* __restrict__ Vt, float* __restrict__ Li,
              bf16* __restrict__ ctxOut)
{
    // 1024 blocks; bid%8 = XCD; each XCD gets 128 consecutive semantic idx
    // = 4 full (h,b) groups -> K/V (512KB each) L2-resident per XCD.
    const int bid = blockIdx.x;
    const int l   = (bid & 7) * 128 + (bid >> 3);
    const int q0  = (l & 31) * 64;
    const int h   = (l >> 5) & 15;
    const int b   = l >> 9;

    const int tid = threadIdx.x;
    const int wv = tid >> 6, lane = tid & 63, quad = lane >> 4, l16 = lane & 15;

    __shared__ bf16 Kl[2][4096];   // [buf][64 j][64 dk]  128B rows, swizzled
    __shared__ bf16 Vl[2][4096];   // [buf][64 d][64 pos] 128B rows, swizzled

    const size_t hb = (size_t)(b * H_ + h) * S_;
    const int qw = q0 + wv * 16;   // this wave's 16 q-rows

    bf16x8 qf0, qf1;
    {
        const bf16* qrow = Q + (hb + qw + l16) * DK_;
        qf0 = ld8(qrow + quad*8);
        qf1 = ld8(qrow + 32 + quad*8);
    }
    const char* Kbc = (const char*)(K  + hb * DK_);
    const char* Vbc = (const char*)(Vt + hb * DK_);  // row d at +d*S*2B

    f32x4 cacc[4];      // [db]  C[dk = db*16+quad*4+r][q = l16]
#pragma unroll
    for (int db = 0; db < 4; ++db) cacc[db] = f32x4{0.f,0.f,0.f,0.f};
    float lsum = 0.f;

    // staging constants: each wave fills rows wv*16..+16 of both tiles via
    // 2 calls x 8 rows (64 lanes x 16B = 1024B). lane -> row +(lane>>3),
    // 16B-unit (lane&7); src unit XOR'd with row&7 (= lane>>3).
    const int rbK  = wv * 16;
    const int rlan = lane >> 3;
    const int off  = (((lane & 7) ^ rlan) << 4);

#define STAGE(jc, buf)                                                        \
    do {                                                                      \
        const size_t jb = (size_t)(jc) * 64;                                  \
        g2l16(Kbc + (jb + rbK + rlan) * 128 + off,      &Kl[buf][rbK*64]);    \
        g2l16(Kbc + (jb + rbK + 8 + rlan) * 128 + off,  &Kl[buf][(rbK+8)*64]);\
        g2l16(Vbc + (size_t)(rbK + rlan) * (S_*2) + jb*2 + off,               \
              &Vl[buf][rbK*64]);                                              \
        g2l16(Vbc + (size_t)(rbK + 8 + rlan) * (S_*2) + jb*2 + off,           \
              &Vl[buf][(rbK+8)*64]);                                          \
    } while (0)

    STAGE(0, 0);
    __syncthreads();   // drains vmcnt(0): buf0 ready

    int cur = 0;
    const int sw = (l16 & 7) << 4;   // read-side XOR key (row&7 == l16&7)
    for (int jc = 0; jc < 32; ++jc) {
        STAGE((jc + 1) & 31, cur ^ 1);   // async; drained at the barrier

        const char* kb = (const char*)&Kl[cur][0];
        const char* vb = (const char*)&Vl[cur][0];

        // QK^T: 4 j-tiles of 16
        f32x4 sc[4];
#pragma unroll
        for (int t = 0; t < 4; ++t) {
            const char* kr = kb + (t*16 + l16) * 128;
            bf16x8 ka = *(const bf16x8*)(kr + ((quad*16) ^ sw));
            bf16x8 kbv = *(const bf16x8*)(kr + ((64 + quad*16) ^ sw));
            f32x4 z = {0.f,0.f,0.f,0.f};
            z = __builtin_amdgcn_mfma_f32_16x16x32_bf16(ka, qf0, z, 0, 0, 0);
            sc[t] = __builtin_amdgcn_mfma_f32_16x16x32_bf16(kbv, qf1, z, 0, 0, 0);
        }

        float ex[4][4];
#pragma unroll
        for (int t = 0; t < 4; ++t)
#pragma unroll
            for (int r = 0; r < 4; ++r)
                ex[t][r] = __builtin_amdgcn_exp2f(fminf(sc[t][r], 86.f));
#pragma unroll
        for (int t = 0; t < 4; ++t)
            lsum += (ex[t][0] + ex[t][1]) + (ex[t][2] + ex[t][3]);

        // pa packing for the interleaved V layout: pa_kc[2r+u] = P[j =
        // 32kc + 16u + 4quad + r]  (tile t = 2kc+u)
        bf16x8 pa0, pa1;
#pragma unroll
        for (int r = 0; r < 4; ++r) {
            pa0[2*r]   = (bf16)ex[0][r];
            pa0[2*r+1] = (bf16)ex[1][r];
            pa1[2*r]   = (bf16)ex[2][r];
            pa1[2*r+1] = (bf16)ex[3][r];
        }

        // PV: one b128 V read per (db, kc)
#pragma unroll
        for (int db = 0; db < 4; ++db) {
            const char* vr = vb + (db*16 + l16) * 128;
            bf16x8 va0 = *(const bf16x8*)(vr + ((quad*16) ^ sw));
            bf16x8 va1 = *(const bf16x8*)(vr + ((64 + quad*16) ^ sw));
            cacc[db] = __builtin_amdgcn_mfma_f32_16x16x32_bf16(
                va0, pa0, cacc[db], 0, 0, 0);
            cacc[db] = __builtin_amdgcn_mfma_f32_16x16x32_bf16(
                va1, pa1, cacc[db], 0, 0, 0);
        }

        __syncthreads();   // drains stage vmcnt + all waves done with cur
        cur ^= 1;
    }
#undef STAGE

    // L reduce across quads (lanes sharing l16): all lanes end with their row
    lsum += __shfl_xor(lsum, 16);
    lsum += __shfl_xor(lsum, 32);
    const float linv = 1.0f / fmaxf(lsum, 1e-30f);
    if (lane < 16) Li[hb + qw + lane] = lsum;

    // normalize + write straight from registers (8B stores, dk contiguous)
#pragma unroll
    for (int db = 0; db < 4; ++db) {
        bf16x4 pk;
#pragma unroll
        for (int r = 0; r < 4; ++r) pk[r] = (bf16)(cacc[db][r] * linv);
        *(bf16x4*)(ctxOut + (hb + qw + l16) * DK_ + db*16 + quad*4) = pk;
    }
}

// ---------------------------------------------------------------------------
// Head-mean attention weights.
// r7 (4w global-K): 72.8us; r8 (more blocks): 102us (2x K traffic); r9 (8w
// global-K): 95.6us (occupancy up, but K still a global-latency load on the
// MFMA chain). Fix: keep r9's 512-block x 8-wave geometry but stage each
// head's K chunk (256j x 128B = 32KB) in DOUBLE-BUFFERED LDS via
// global_load_lds, prefetching head h+1 during head h's compute (one barrier
// per h; per-h compute >> load latency so the barrier drain is covered).
// Reads use the validated byte^=(row&7)<<4 b128 swizzle; source pre-swizzled
// (rule #21). Q loads stay global (L1-hot, all 8 waves share 64 rows).
// LDS 2x32KB + 4KB linv = 68KB -> 2 blocks/CU = 16 waves/CU.
// Swapped QK^T: lane holds 4 CONSECUTIVE j for its q -> f32x4 stores; linv
// hoisted per (h,q) with 1/H folded in; bare exp2 (scale folded into Q).
// ---------------------------------------------------------------------------
__global__ __launch_bounds__(512)
void attn_weights(const bf16* __restrict__ Q, const bf16* __restrict__ K,
                  const float* __restrict__ Li, float* __restrict__ attnOut)
{
    // 512 blocks: l = q-tile (32) x b (2) x j-chunk (8); each XCD gets 64
    // consecutive l = one j-chunk, both b. Bijective.
    const int bid = blockIdx.x;
    const int l   = (bid & 7) * 64 + (bid >> 3);
    const int q0  = (l & 31) * 64;
    const int b   = (l >> 5) & 1;
    const int j0  = (l >> 6) * 256;

    const int tid = threadIdx.x;
    const int wv = tid >> 6, lane = tid & 63, quad = lane >> 4, l16 = lane & 15;

    __shared__ bf16 Klds[2][256 * 64];   // [buf][j][dk] 32KB each, swizzled
    __shared__ float linv[H_][64];
    {
        int idx = tid * 2;
        int hh = idx >> 6, row = idx & 63;
        const float* Lp = Li + (size_t)(b * H_ + hh) * S_ + q0 + row;
        linv[hh][row]     = (1.0f / H_) / fmaxf(Lp[0], 1e-30f);
        linv[hh][row + 1] = (1.0f / H_) / fmaxf(Lp[1], 1e-30f);
    }

    // staging: wave wv fills rows wv*32..+32 (4 calls x 8 rows; 64 lanes x
    // 16B = 1KB = 8 rows). lane -> row +(lane>>3); 16B-unit (lane&7) holds
    // source unit (lane&7)^(row&7)  [row&7 == lane>>3].
    const int rlan = lane >> 3;
    const int off  = (((lane & 7) ^ rlan) << 4);
    const char* Kbase = (const char*)(K + ((size_t)(b * H_) * S_ + j0) * DK_);
    // head h rows start at Kbase + h*S*128; row j (in-chunk) at +j*128

#define WSTAGE(h, buf)                                                        \
    do {                                                                      \
        const char* src = Kbase + (size_t)(h) * (S_ * 128);                   \
        for (int c = 0; c < 4; ++c) {                                         \
            const int rr = wv * 32 + c * 8;                                   \
            g2l16(src + (size_t)(rr + rlan) * 128 + off, &Klds[buf][rr * 64]);\
        }                                                                     \
    } while (0)

    WSTAGE(0, 0);
    __syncthreads();   // drains vmcnt(0): buf0 ready

    f32x4 asum[4][2];
#pragma unroll
    for (int qt = 0; qt < 4; ++qt)
#pragma unroll
        for (int t = 0; t < 2; ++t) asum[qt][t] = f32x4{0.f,0.f,0.f,0.f};

    int cur = 0;
    const int sw = (l16 & 7) << 4;   // read-side XOR key (row&7 == l16&7)
    for (int h = 0; h < H_; ++h) {
        WSTAGE((h + 1) & 15, cur ^ 1);   // async; drained at the barrier

        const size_t hb = (size_t)(b * H_ + h) * S_;
        bf16x8 qf[4][2];
        float lv[4];
#pragma unroll
        for (int qt = 0; qt < 4; ++qt) {
            const bf16* qrow = Q + (hb + q0 + qt*16 + l16) * DK_;
            qf[qt][0] = ld8(qrow + quad*8);
            qf[qt][1] = ld8(qrow + 32 + quad*8);
            lv[qt] = linv[h][qt*16 + l16];
        }

        const char* kb = (const char*)&Klds[cur][0];
#pragma unroll
        for (int t = 0; t < 2; ++t) {
            const char* kr = kb + (wv*32 + t*16 + l16) * 128;
            bf16x8 kfa = *(const bf16x8*)(kr + ((quad*16) ^ sw));
            bf16x8 kfb = *(const bf16x8*)(kr + ((64 + quad*16) ^ sw));
#pragma unroll
            for (int qt = 0; qt < 4; ++qt) {
                f32x4 z = {0.f,0.f,0.f,0.f};
                z = __builtin_amdgcn_mfma_f32_16x16x32_bf16(kfa, qf[qt][0], z, 0, 0, 0);
                f32x4 s = __builtin_amdgcn_mfma_f32_16x16x32_bf16(kfb, qf[qt][1], z, 0, 0, 0);
#pragma unroll
                for (int r = 0; r < 4; ++r)
                    asum[qt][t][r] += __builtin_amdgcn_exp2f(fminf(s[r], 86.f)) * lv[qt];
            }
        }
        __syncthreads();   // stage of cur^1 done + all waves done with cur
        cur ^= 1;
    }
#undef WSTAGE

#pragma unroll
    for (int qt = 0; qt < 4; ++qt)
#pragma unroll
        for (int t = 0; t < 2; ++t)
            *(f32x4*)(attnOut + ((size_t)b * S_ + q0 + qt*16 + l16) * S_
                      + j0 + wv*32 + t*16 + quad*4) = asum[qt][t];
}

// ---------------------------------------------------------------------------
extern "C" void kernel_launch(void* const* d_in, const int* in_sizes, int n_in,
                              void* d_out, int out_size, void* d_ws, size_t ws_size,
                              hipStream_t stream)
{
    (void)in_sizes; (void)n_in; (void)out_size; (void)ws_size;

    const float* query = (const float*)d_in[0];
    const float* key_t = (const float*)d_in[1];
    const float* value = (const float*)d_in[2];
    const float* Wq = (const float*)d_in[3];
    const float* bq = (const float*)d_in[4];
    const float* Wk = (const float*)d_in[5];
    const float* bk = (const float*)d_in[6];
    const float* Wv = (const float*)d_in[7];
    const float* bv = (const float*)d_in[8];
    const float* Wo = (const float*)d_in[9];
    const float* bo = (const float*)d_in[10];

    float* out     = (float*)d_out;                  // (B,S,D) fp32
    float* attnOut = out + (size_t)B_ * S_ * D_;     // (B,S,S) fp32

    const size_t nX = (size_t)B_ * S_ * D_;
    const size_t nW = (size_t)D_ * D_;

    // d_out doubles as scratch for bf16 X-converts (dead before overwrites)
    bf16* Xqb = (bf16*)d_out;
    bf16* Xkb = Xqb + nX;
    bf16* Xvb = Xkb + nX;

    // ws: Qh,Kh,VtH (25.2MB) + Wob (2.1MB) + Li (0.26MB) + [Wqb/Wkb/Wvb
    // overlaid by CtxH (8.4MB) -- W converts are dead before attn_ctx runs].
    bf16* Qh  = (bf16*)d_ws;
    bf16* Kh  = Qh + nX;
    bf16* VtH = Kh + nX;                 // V^T (B,H,DK,S), pair-interleaved
    bf16* Wob = VtH + nX;
    float* Li = (float*)(Wob + nW);
    bf16* Wqb = (bf16*)(Li + (size_t)B_ * H_ * S_);
    bf16* Wkb = Wqb + nW;
    bf16* Wvb = Wkb + nW;
    bf16* CtxH = Wqb;                                // overlays dead W converts

    cvt_all<<<8192, 256, 0, stream>>>(query, key_t, value, Wq, Wk, Wv, Wo,
                                      Xqb, Xkb, Xvb, Wqb, Wkb, Wvb, Wob);
    dim3 gg(M_/128, D_/128);
    // Q pre-scaled by 1/sqrt(DK) * log2(e): softmax scale + exp->exp2 fold
    gemm128<<<gg, 256, 0, stream>>>(Xqb, Wqb, bq, Qh, 0, 0, 0.18033688011112042f);
    gemm128<<<gg, 256, 0, stream>>>(Xkb, Wkb, bk, Kh, 0, 0, 1.0f);
    gemm128<<<gg, 256, 0, stream>>>(Xvb, Wvb, bv, VtH, 0, 2, 1.0f);   // V^T
    attn_ctx    <<<1024, 256, 0, stream>>>(Qh, Kh, VtH, Li, CtxH);
    attn_weights<<<512, 512, 0, stream>>>(Qh, Kh, Li, attnOut);
    gemm128<<<gg, 256, 0, stream>>>(CtxH, Wob, bo, out, 1, 1, 1.0f);
}

// Round 12
// 341.510 us; speedup vs baseline: 1.1014x; 1.0391x over previous
//
#include <hip/hip_runtime.h>

// Problem constants (B,S,D,H from reference)
#define B_ 2
#define S_ 2048
#define D_ 1024
#define H_ 16
#define DK_ 64
#define M_ (B_ * S_)      // 4096 rows in the projection GEMMs

typedef __bf16 bf16;
typedef __attribute__((ext_vector_type(8))) __bf16 bf16x8;
typedef __attribute__((ext_vector_type(4))) __bf16 bf16x4;
typedef __attribute__((ext_vector_type(4))) float f32x4;

static __device__ __forceinline__ bf16x8 ld8(const bf16* p) {
    return *(const bf16x8*)p;   // 16B aligned by construction
}

// Async global->LDS, 16B per lane. LDS dest = wave-uniform base + lane*16
// (linear); global src is per-lane (carries the swizzle).
static __device__ __forceinline__ void g2l16(const void* g, void* l) {
    __builtin_amdgcn_global_load_lds(
        (const __attribute__((address_space(1))) unsigned int*)g,
        (__attribute__((address_space(3))) unsigned int*)l, 16, 0, 0);
}

// ---------------------------------------------------------------------------
// Elementwise fp32 -> bf16 for the 3 X inputs (into d_out scratch) and the
// 4 weight matrices (into ws). Block mapping: 3*2048 X-blocks + 4*512 W-blocks.
// ---------------------------------------------------------------------------
__global__ __launch_bounds__(256)
void cvt_all(const float* __restrict__ xq, const float* __restrict__ xk,
             const float* __restrict__ xv, const float* __restrict__ wq,
             const float* __restrict__ wk, const float* __restrict__ wv,
             const float* __restrict__ wo, bf16* __restrict__ xqo,
             bf16* __restrict__ xko, bf16* __restrict__ xvo,
             bf16* __restrict__ wqo, bf16* __restrict__ wko,
             bf16* __restrict__ wvo, bf16* __restrict__ woo)
{
    const int bx = blockIdx.x;
    const float* s; bf16* d; size_t base;
    if (bx < 6144) {
        int a = bx >> 11;
        s = (a == 0) ? xq : (a == 1) ? xk : xv;
        d = (a == 0) ? xqo : (a == 1) ? xko : xvo;
        base = (size_t)(bx & 2047) * 2048;
    } else {
        int a = (bx - 6144) >> 9;
        s = (a == 0) ? wq : (a == 1) ? wk : (a == 2) ? wv : wo;
        d = (a == 0) ? wqo : (a == 1) ? wko : (a == 2) ? wvo : woo;
        base = (size_t)((bx - 6144) & 511) * 2048;
    }
    size_t i = base + (size_t)threadIdx.x * 8;
    f32x4 a4 = *(const f32x4*)(s + i);
    f32x4 b4 = *(const f32x4*)(s + i + 4);
    bf16x8 r;
    r[0]=(bf16)a4[0]; r[1]=(bf16)a4[1]; r[2]=(bf16)a4[2]; r[3]=(bf16)a4[3];
    r[4]=(bf16)b4[0]; r[5]=(bf16)b4[1]; r[6]=(bf16)b4[2]; r[7]=(bf16)b4[3];
    *(bf16x8*)(d + i) = r;
}

// ---------------------------------------------------------------------------
// 128x128-tile bf16 GEMM, LDS-staged, 2-barrier K-loop.
// out_mode: 0 = bf16 head-split (B,H,S,DK);  1 = fp32 flat (M,N);
//           2 = bf16 V^T head-split (B,H,DK,S) with PAIR-INTERLEAVED tokens:
//               within each 32-token block, element order is
//               (j0,j0+16,j0+1,j0+17,...,j0+15,j0+31)  [pos=2*(j&15)+(j>>4)].
//               This makes attn_ctx's PV fragment one contiguous 16B read.
// a_headsplit: A element (m,k) at ((b*H+h)*S+s)*DK+dk (ctx layout).
// scale: applied after bias. Q gemm folds 0.125*log2(e) (softmax 1/sqrt(DK)
//        plus the exp->exp2 conversion factor).
// ---------------------------------------------------------------------------
__global__ __launch_bounds__(256)
void gemm128(const bf16* __restrict__ A, const bf16* __restrict__ W,
             const float* __restrict__ bias, void* __restrict__ out,
             int a_headsplit, int out_mode, float scale)
{
    const int m0 = blockIdx.x * 128, n0 = blockIdx.y * 128;
    const int tid = threadIdx.x;
    const int wv = tid >> 6, lane = tid & 63, quad = lane >> 4, l16 = lane & 15;
    const int wr = (wv >> 1) * 64, wc = (wv & 1) * 64;

    __shared__ bf16 As[128 * 32];
    __shared__ bf16 Bs[128 * 32];

    f32x4 acc[4][4];
#pragma unroll
    for (int i = 0; i < 4; ++i)
#pragma unroll
        for (int j = 0; j < 4; ++j) acc[i][j] = f32x4{0.f, 0.f, 0.f, 0.f};

    const int srow = tid >> 2;
    const int scol = (tid & 3) * 8;

    for (int k0 = 0; k0 < D_; k0 += 32) {
        bf16x8 av[2], bw[2];
#pragma unroll
        for (int c = 0; c < 2; ++c) {
            const int row = c * 64 + srow;
            const int k   = k0 + scol;
            const bf16* ap;
            if (a_headsplit) {
                int m = m0 + row, bb = m >> 11, ss = m & (S_ - 1);
                int hh = k >> 6, dd = k & (DK_ - 1);
                ap = A + (((size_t)(bb * H_ + hh) * S_ + ss) * DK_ + dd);
            } else {
                ap = A + (size_t)(m0 + row) * D_ + k;
            }
            av[c] = ld8(ap);
            bw[c] = ld8(W + (size_t)(n0 + row) * D_ + k);
        }
        __syncthreads();
#pragma unroll
        for (int c = 0; c < 2; ++c) {
            const int e = c * 2048 + tid * 8;
            *(bf16x8*)(As + e) = av[c];
            *(bf16x8*)(Bs + e) = bw[c];
        }
        __syncthreads();

        bf16x8 af[4], bfr[4];
#pragma unroll
        for (int i = 0; i < 4; ++i)
            af[i] = *(const bf16x8*)(As + (wr + i*16 + l16) * 32 + quad * 8);
#pragma unroll
        for (int j = 0; j < 4; ++j)
            bfr[j] = *(const bf16x8*)(Bs + (wc + j*16 + l16) * 32 + quad * 8);
#pragma unroll
        for (int i = 0; i < 4; ++i)
#pragma unroll
            for (int j = 0; j < 4; ++j)
                acc[i][j] = __builtin_amdgcn_mfma_f32_16x16x32_bf16(
                    af[i], bfr[j], acc[i][j], 0, 0, 0);
    }

    if (out_mode == 2) {
        // V^T pair-interleaved: i-tiles 2ip (tokens s..s+15 region) and 2ip+1
        // (s+16..s+31) share a 32-token block; interleaving their r-elements
        // gives one contiguous 16B store at pos-base 2*(s&15).
#pragma unroll
        for (int j = 0; j < 4; ++j) {
            const int nn = n0 + wc + j*16 + l16;      // d index
            const float bvv = bias[nn];
            int hh = nn >> 6, dd = nn & (DK_ - 1);
#pragma unroll
            for (int ip = 0; ip < 2; ++ip) {
                const int mlo = m0 + wr + 32*ip + quad*4;   // token of (2ip, r=0)
                int bb = mlo >> 11, sl = mlo & (S_ - 1);
                int g0 = (sl & ~31) + ((sl & 15) << 1);
                bf16x8 pk;
#pragma unroll
                for (int r = 0; r < 4; ++r) {
                    pk[2*r]   = (bf16)((acc[2*ip  ][j][r] + bvv) * scale);
                    pk[2*r+1] = (bf16)((acc[2*ip+1][j][r] + bvv) * scale);
                }
                *(bf16x8*)((bf16*)out +
                    ((size_t)(bb * H_ + hh) * DK_ + dd) * S_ + g0) = pk;
            }
        }
    } else {
#pragma unroll
        for (int i = 0; i < 4; ++i)
#pragma unroll
            for (int j = 0; j < 4; ++j) {
                const int nn = n0 + wc + j*16 + l16;
                const float bvv = bias[nn];
                const int mm0 = m0 + wr + i*16 + quad*4;   // 4-aligned, same b
#pragma unroll
                for (int r = 0; r < 4; ++r) {
                    const int mm = mm0 + r;
                    float v = (acc[i][j][r] + bvv) * scale;
                    if (out_mode == 1) {
                        ((float*)out)[(size_t)mm * D_ + nn] = v;
                    } else {
                        int bb = mm >> 11, ss = mm & (S_ - 1);
                        int hh = nn >> 6, dd = nn & (DK_ - 1);
                        ((bf16*)out)[((size_t)(bb * H_ + hh) * S_ + ss) * DK_ + dd] = (bf16)v;
                    }
                }
            }
    }
}

// ---------------------------------------------------------------------------
// Context + softmax denominators, fused.
// Block = 64 q-rows, one (h,b); 4 waves; each wave owns 16 q-rows over the
// full j-range (no cross-wave reduce). K and interleaved-V^T staged in 64-j
// chunks via global_load_lds into double-buffered LDS; BOTH tiles are
// [64 rows][128B] read as ds_read_b128 with the validated byte^=(row&7)<<4
// swizzle. Swizzle applied on the per-lane GLOBAL source address (linear LDS
// dest, rule #21) and re-applied on the read side.
// Swapped QK^T: s = mfma(K,Q) puts P[j=16t+4q+r][q-col=l16] in registers; PV
// pa packing follows the interleaved k->j bijection, so P feeds PV straight
// from registers. Scores pre-scaled by 0.125*log2e -> bare v_exp2. P~
// UNNORMALIZED; row-sum L reduced with 2 shuffles; ctx written from regs.
// ---------------------------------------------------------------------------
__global__ __launch_bounds__(256)
void attn_ctx(const bf16* __restrict__ Q, const bf16* __restrict__ K,
              const bf16* __restrict__ Vt, float* __restrict__ Li,
              bf16* __restrict__ ctxOut)
{
    // 1024 blocks; bid%8 = XCD; each XCD gets 128 consecutive semantic idx
    // = 4 full (h,b) groups -> K/V (512KB each) L2-resident per XCD.
    const int bid = blockIdx.x;
    const int l   = (bid & 7) * 128 + (bid >> 3);
    const int q0  = (l & 31) * 64;
    const int h   = (l >> 5) & 15;
    const int b   = l >> 9;

    const int tid = threadIdx.x;
    const int wv = tid >> 6, lane = tid & 63, quad = lane >> 4, l16 = lane & 15;

    __shared__ bf16 Kl[2][4096];   // [buf][64 j][64 dk]  128B rows, swizzled
    __shared__ bf16 Vl[2][4096];   // [buf][64 d][64 pos] 128B rows, swizzled

    const size_t hb = (size_t)(b * H_ + h) * S_;
    const int qw = q0 + wv * 16;   // this wave's 16 q-rows

    bf16x8 qf0, qf1;
    {
        const bf16* qrow = Q + (hb + qw + l16) * DK_;
        qf0 = ld8(qrow + quad*8);
        qf1 = ld8(qrow + 32 + quad*8);
    }
    const char* Kbc = (const char*)(K  + hb * DK_);
    const char* Vbc = (const char*)(Vt + hb * DK_);  // row d at +d*S*2B

    f32x4 cacc[4];      // [db]  C[dk = db*16+quad*4+r][q = l16]
#pragma unroll
    for (int db = 0; db < 4; ++db) cacc[db] = f32x4{0.f,0.f,0.f,0.f};
    float lsum = 0.f;

    // staging constants: each wave fills rows wv*16..+16 of both tiles via
    // 2 calls x 8 rows (64 lanes x 16B = 1024B). lane -> row +(lane>>3),
    // 16B-unit (lane&7); src unit XOR'd with row&7 (= lane>>3).
    const int rbK  = wv * 16;
    const int rlan = lane >> 3;
    const int off  = (((lane & 7) ^ rlan) << 4);

#define STAGE(jc, buf)                                                        \
    do {                                                                      \
        const size_t jb = (size_t)(jc) * 64;                                  \
        g2l16(Kbc + (jb + rbK + rlan) * 128 + off,      &Kl[buf][rbK*64]);    \
        g2l16(Kbc + (jb + rbK + 8 + rlan) * 128 + off,  &Kl[buf][(rbK+8)*64]);\
        g2l16(Vbc + (size_t)(rbK + rlan) * (S_*2) + jb*2 + off,               \
              &Vl[buf][rbK*64]);                                              \
        g2l16(Vbc + (size_t)(rbK + 8 + rlan) * (S_*2) + jb*2 + off,           \
              &Vl[buf][(rbK+8)*64]);                                          \
    } while (0)

    STAGE(0, 0);
    __syncthreads();   // drains vmcnt(0): buf0 ready

    int cur = 0;
    const int sw = (l16 & 7) << 4;   // read-side XOR key (row&7 == l16&7)
    for (int jc = 0; jc < 32; ++jc) {
        STAGE((jc + 1) & 31, cur ^ 1);   // async; drained at the barrier

        const char* kb = (const char*)&Kl[cur][0];
        const char* vb = (const char*)&Vl[cur][0];

        // QK^T: 4 j-tiles of 16
        f32x4 sc[4];
#pragma unroll
        for (int t = 0; t < 4; ++t) {
            const char* kr = kb + (t*16 + l16) * 128;
            bf16x8 ka = *(const bf16x8*)(kr + ((quad*16) ^ sw));
            bf16x8 kbv = *(const bf16x8*)(kr + ((64 + quad*16) ^ sw));
            f32x4 z = {0.f,0.f,0.f,0.f};
            z = __builtin_amdgcn_mfma_f32_16x16x32_bf16(ka, qf0, z, 0, 0, 0);
            sc[t] = __builtin_amdgcn_mfma_f32_16x16x32_bf16(kbv, qf1, z, 0, 0, 0);
        }

        float ex[4][4];
#pragma unroll
        for (int t = 0; t < 4; ++t)
#pragma unroll
            for (int r = 0; r < 4; ++r)
                ex[t][r] = __builtin_amdgcn_exp2f(fminf(sc[t][r], 86.f));
#pragma unroll
        for (int t = 0; t < 4; ++t)
            lsum += (ex[t][0] + ex[t][1]) + (ex[t][2] + ex[t][3]);

        // pa packing for the interleaved V layout: pa_kc[2r+u] = P[j =
        // 32kc + 16u + 4quad + r]  (tile t = 2kc+u)
        bf16x8 pa0, pa1;
#pragma unroll
        for (int r = 0; r < 4; ++r) {
            pa0[2*r]   = (bf16)ex[0][r];
            pa0[2*r+1] = (bf16)ex[1][r];
            pa1[2*r]   = (bf16)ex[2][r];
            pa1[2*r+1] = (bf16)ex[3][r];
        }

        // PV: one b128 V read per (db, kc)
#pragma unroll
        for (int db = 0; db < 4; ++db) {
            const char* vr = vb + (db*16 + l16) * 128;
            bf16x8 va0 = *(const bf16x8*)(vr + ((quad*16) ^ sw));
            bf16x8 va1 = *(const bf16x8*)(vr + ((64 + quad*16) ^ sw));
            cacc[db] = __builtin_amdgcn_mfma_f32_16x16x32_bf16(
                va0, pa0, cacc[db], 0, 0, 0);
            cacc[db] = __builtin_amdgcn_mfma_f32_16x16x32_bf16(
                va1, pa1, cacc[db], 0, 0, 0);
        }

        __syncthreads();   // drains stage vmcnt + all waves done with cur
        cur ^= 1;
    }
#undef STAGE

    // L reduce across quads (lanes sharing l16): all lanes end with their row
    lsum += __shfl_xor(lsum, 16);
    lsum += __shfl_xor(lsum, 32);
    const float linv = 1.0f / fmaxf(lsum, 1e-30f);
    if (lane < 16) Li[hb + qw + lane] = lsum;

    // normalize + write straight from registers (8B stores, dk contiguous)
#pragma unroll
    for (int db = 0; db < 4; ++db) {
        bf16x4 pk;
#pragma unroll
        for (int r = 0; r < 4; ++r) pk[r] = (bf16)(cacc[db][r] * linv);
        *(bf16x4*)(ctxOut + (hb + qw + l16) * DK_ + db*16 + quad*4) = pk;
    }
}

// ---------------------------------------------------------------------------
// Head-mean attention weights.
// History: r7 (4w/64j, global K, 19% occ) 72.8us BEST; r8 (more blocks)
// 102us; r9 (8w/32j, 34% occ) 95.6us; r10 (8w + LDS K, 36% occ) 83.7us.
// Occupancy rose monotonically yet r7 stayed fastest -> the lever is
// PER-WAVE ILP, not TLP. All rounds showed VGPR 56-68: compiler allocated
// minimal registers and serialized each load->MFMA->exp chain.
// This version: r7 geometry + explicit software pipeline. Per h-iteration:
// (1) ALL 4 t-tiles' K fragments loaded up-front (8xb128; first MFMA waits
// only on the first via counted vmcnt, rest stay in flight); (2) Q[h+1]
// prefetched into separate regs, consumed next iteration ((h+1)&15 wrap,
// branchless); (3) 16 independent (t,qt) MFMA->exp chains compiled with
// ~180 VGPR of live state. Grid-limited 2 waves/SIMD is fine -- the in-
// flight loads do the latency hiding, not extra waves.
// Swapped QK^T: lane holds 4 CONSECUTIVE j for its q -> f32x4 stores; linv
// hoisted per (h,q) with 1/H folded in; bare exp2 (scale folded into Q).
// ---------------------------------------------------------------------------
__global__ __launch_bounds__(256)
void attn_weights(const bf16* __restrict__ Q, const bf16* __restrict__ K,
                  const float* __restrict__ Li, float* __restrict__ attnOut)
{
    // 512 blocks: l = q-tile (32) x b (2) x j-chunk (8); each XCD gets 64
    // consecutive l = one j-chunk, both b. Bijective.
    const int bid = blockIdx.x;
    const int l   = (bid & 7) * 64 + (bid >> 3);
    const int q0  = (l & 31) * 64;
    const int b   = (l >> 5) & 1;
    const int j0  = (l >> 6) * 256;

    const int tid = threadIdx.x;
    const int wv = tid >> 6, lane = tid & 63, quad = lane >> 4, l16 = lane & 15;

    __shared__ float linv[H_][64];
#pragma unroll
    for (int i = 0; i < 4; ++i) {
        int idx = tid * 4 + i;
        int hh = idx >> 6, row = idx & 63;
        linv[hh][row] = (1.0f / H_) /
            fmaxf(Li[(size_t)(b * H_ + hh) * S_ + q0 + row], 1e-30f);
    }
    __syncthreads();

    f32x4 asum[4][4];
#pragma unroll
    for (int qt = 0; qt < 4; ++qt)
#pragma unroll
        for (int t = 0; t < 4; ++t) asum[qt][t] = f32x4{0.f,0.f,0.f,0.f};

    // Q fragments for h=0 (current set)
    bf16x8 qc[4][2];
    {
        const size_t hb0 = (size_t)(b * H_) * S_;
#pragma unroll
        for (int qt = 0; qt < 4; ++qt) {
            const bf16* qrow = Q + (hb0 + q0 + qt*16 + l16) * DK_;
            qc[qt][0] = ld8(qrow + quad*8);
            qc[qt][1] = ld8(qrow + 32 + quad*8);
        }
    }

    for (int h = 0; h < H_; ++h) {
        const size_t hb = (size_t)(b * H_ + h) * S_;

        // --- issue ALL K loads for this h (4 t-tiles, 8 b128) up-front ---
        bf16x8 kA[4], kB[4];
#pragma unroll
        for (int t = 0; t < 4; ++t) {
            const bf16* krow = K + (hb + (size_t)(j0 + wv*64 + t*16 + l16)) * DK_;
            kA[t] = ld8(krow + quad*8);
            kB[t] = ld8(krow + 32 + quad*8);
        }

        // --- prefetch Q for h+1 (consumed next iteration; wraps at h=15) ---
        bf16x8 qn[4][2];
        {
            const size_t hbn = (size_t)(b * H_ + ((h + 1) & 15)) * S_;
#pragma unroll
            for (int qt = 0; qt < 4; ++qt) {
                const bf16* qrow = Q + (hbn + q0 + qt*16 + l16) * DK_;
                qn[qt][0] = ld8(qrow + quad*8);
                qn[qt][1] = ld8(qrow + 32 + quad*8);
            }
        }

        float lv[4];
#pragma unroll
        for (int qt = 0; qt < 4; ++qt) lv[qt] = linv[h][qt*16 + l16];

        // --- 16 independent (t,qt) chains ---
#pragma unroll
        for (int t = 0; t < 4; ++t)
#pragma unroll
            for (int qt = 0; qt < 4; ++qt) {
                f32x4 z = {0.f,0.f,0.f,0.f};
                z = __builtin_amdgcn_mfma_f32_16x16x32_bf16(kA[t], qc[qt][0], z, 0, 0, 0);
                f32x4 s = __builtin_amdgcn_mfma_f32_16x16x32_bf16(kB[t], qc[qt][1], z, 0, 0, 0);
#pragma unroll
                for (int r = 0; r < 4; ++r)
                    asum[qt][t][r] += __builtin_amdgcn_exp2f(fminf(s[r], 86.f)) * lv[qt];
            }

        // rotate prefetched Q into current
#pragma unroll
        for (int qt = 0; qt < 4; ++qt) {
            qc[qt][0] = qn[qt][0];
            qc[qt][1] = qn[qt][1];
        }
    }

#pragma unroll
    for (int qt = 0; qt < 4; ++qt)
#pragma unroll
        for (int t = 0; t < 4; ++t)
            *(f32x4*)(attnOut + ((size_t)b * S_ + q0 + qt*16 + l16) * S_
                      + j0 + wv*64 + t*16 + quad*4) = asum[qt][t];
}

// ---------------------------------------------------------------------------
extern "C" void kernel_launch(void* const* d_in, const int* in_sizes, int n_in,
                              void* d_out, int out_size, void* d_ws, size_t ws_size,
                              hipStream_t stream)
{
    (void)in_sizes; (void)n_in; (void)out_size; (void)ws_size;

    const float* query = (const float*)d_in[0];
    const float* key_t = (const float*)d_in[1];
    const float* value = (const float*)d_in[2];
    const float* Wq = (const float*)d_in[3];
    const float* bq = (const float*)d_in[4];
    const float* Wk = (const float*)d_in[5];
    const float* bk = (const float*)d_in[6];
    const float* Wv = (const float*)d_in[7];
    const float* bv = (const float*)d_in[8];
    const float* Wo = (const float*)d_in[9];
    const float* bo = (const float*)d_in[10];

    float* out     = (float*)d_out;                  // (B,S,D) fp32
    float* attnOut = out + (size_t)B_ * S_ * D_;     // (B,S,S) fp32

    const size_t nX = (size_t)B_ * S_ * D_;
    const size_t nW = (size_t)D_ * D_;

    // d_out doubles as scratch for bf16 X-converts (dead before overwrites)
    bf16* Xqb = (bf16*)d_out;
    bf16* Xkb = Xqb + nX;
    bf16* Xvb = Xkb + nX;

    // ws: Qh,Kh,VtH (25.2MB) + Wob (2.1MB) + Li (0.26MB) + [Wqb/Wkb/Wvb
    // overlaid by CtxH (8.4MB) -- W converts are dead before attn_ctx runs].
    bf16* Qh  = (bf16*)d_ws;
    bf16* Kh  = Qh + nX;
    bf16* VtH = Kh + nX;                 // V^T (B,H,DK,S), pair-interleaved
    bf16* Wob = VtH + nX;
    float* Li = (float*)(Wob + nW);
    bf16* Wqb = (bf16*)(Li + (size_t)B_ * H_ * S_);
    bf16* Wkb = Wqb + nW;
    bf16* Wvb = Wkb + nW;
    bf16* CtxH = Wqb;                                // overlays dead W converts

    cvt_all<<<8192, 256, 0, stream>>>(query, key_t, value, Wq, Wk, Wv, Wo,
                                      Xqb, Xkb, Xvb, Wqb, Wkb, Wvb, Wob);
    dim3 gg(M_/128, D_/128);
    // Q pre-scaled by 1/sqrt(DK) * log2(e): softmax scale + exp->exp2 fold
    gemm128<<<gg, 256, 0, stream>>>(Xqb, Wqb, bq, Qh, 0, 0, 0.18033688011112042f);
    gemm128<<<gg, 256, 0, stream>>>(Xkb, Wkb, bk, Kh, 0, 0, 1.0f);
    gemm128<<<gg, 256, 0, stream>>>(Xvb, Wvb, bv, VtH, 0, 2, 1.0f);   // V^T
    attn_ctx    <<<1024, 256, 0, stream>>>(Qh, Kh, VtH, Li, CtxH);
    attn_weights<<<512, 256, 0, stream>>>(Qh, Kh, Li, attnOut);
    gemm128<<<gg, 256, 0, stream>>>(CtxH, Wob, bo, out, 1, 1, 1.0f);
}

// Round 13
// 317.315 us; speedup vs baseline: 1.1854x; 1.0762x over previous
//
#include <hip/hip_runtime.h>

// Problem constants (B,S,D,H from reference)
#define B_ 2
#define S_ 2048
#define D_ 1024
#define H_ 16
#define DK_ 64
#define M_ (B_ * S_)      // 4096 rows in the projection GEMMs

typedef __bf16 bf16;
typedef __attribute__((ext_vector_type(8))) __bf16 bf16x8;
typedef __attribute__((ext_vector_type(4))) __bf16 bf16x4;
typedef __attribute__((ext_vector_type(4))) float f32x4;

static __device__ __forceinline__ bf16x8 ld8(const bf16* p) {
    return *(const bf16x8*)p;   // 16B aligned by construction
}

// Async global->LDS, 16B per lane. LDS dest = wave-uniform base + lane*16
// (linear); global src is per-lane.
static __device__ __forceinline__ void g2l16(const void* g, void* l) {
    __builtin_amdgcn_global_load_lds(
        (const __attribute__((address_space(1))) unsigned int*)g,
        (__attribute__((address_space(3))) unsigned int*)l, 16, 0, 0);
}

// ---------------------------------------------------------------------------
// Elementwise fp32 -> bf16 for the 3 X inputs (into d_out scratch) and the
// 4 weight matrices (into ws). Block mapping: 3*2048 X-blocks + 4*512 W-blocks.
// ---------------------------------------------------------------------------
__global__ __launch_bounds__(256)
void cvt_all(const float* __restrict__ xq, const float* __restrict__ xk,
             const float* __restrict__ xv, const float* __restrict__ wq,
             const float* __restrict__ wk, const float* __restrict__ wv,
             const float* __restrict__ wo, bf16* __restrict__ xqo,
             bf16* __restrict__ xko, bf16* __restrict__ xvo,
             bf16* __restrict__ wqo, bf16* __restrict__ wko,
             bf16* __restrict__ wvo, bf16* __restrict__ woo)
{
    const int bx = blockIdx.x;
    const float* s; bf16* d; size_t base;
    if (bx < 6144) {
        int a = bx >> 11;
        s = (a == 0) ? xq : (a == 1) ? xk : xv;
        d = (a == 0) ? xqo : (a == 1) ? xko : xvo;
        base = (size_t)(bx & 2047) * 2048;
    } else {
        int a = (bx - 6144) >> 9;
        s = (a == 0) ? wq : (a == 1) ? wk : (a == 2) ? wv : wo;
        d = (a == 0) ? wqo : (a == 1) ? wko : (a == 2) ? wvo : woo;
        base = (size_t)((bx - 6144) & 511) * 2048;
    }
    size_t i = base + (size_t)threadIdx.x * 8;
    f32x4 a4 = *(const f32x4*)(s + i);
    f32x4 b4 = *(const f32x4*)(s + i + 4);
    bf16x8 r;
    r[0]=(bf16)a4[0]; r[1]=(bf16)a4[1]; r[2]=(bf16)a4[2]; r[3]=(bf16)a4[3];
    r[4]=(bf16)b4[0]; r[5]=(bf16)b4[1]; r[6]=(bf16)b4[2]; r[7]=(bf16)b4[3];
    *(bf16x8*)(d + i) = r;
}

// ---------------------------------------------------------------------------
// Batched Q/K/V projection GEMM. Round-12 post-mortem: the three separate
// 128x128-tile launches were 256 blocks each = 1 block/CU = 1 wave/SIMD --
// zero latency hiding, ~40us each (~half the total pipeline). This kernel
// runs all three in ONE 768-block launch (3 blocks/CU, 3 waves/SIMD) with
// m97-style async global_load_lds staging into double-buffered LDS (linear
// dest; 1 barrier per K-step -- the compiler's pre-barrier vmcnt(0) drains
// the async loads; pattern proven in attn_ctx r6-r12).
// which=0: Q out (headsplit bf16, scale 0.125*log2e folded for exp2)
// which=1: K out (headsplit bf16)
// which=2: V out (B,H,DK,S) PAIR-INTERLEAVED: pos = 2*(j&15) + (j>>4) within
//          each 32-token block (one contiguous 16B PV fragment in attn_ctx).
// ---------------------------------------------------------------------------
__global__ __launch_bounds__(256)
void gemm_qkv(const bf16* __restrict__ Xq, const bf16* __restrict__ Xk,
              const bf16* __restrict__ Xv, const bf16* __restrict__ Wq,
              const bf16* __restrict__ Wk, const bf16* __restrict__ Wv,
              const float* __restrict__ bq, const float* __restrict__ bk,
              const float* __restrict__ bv, bf16* __restrict__ Qo,
              bf16* __restrict__ Ko, bf16* __restrict__ Vo)
{
    const int bid = blockIdx.x;
    const int which = bid >> 8;          // 0=Q 1=K 2=V
    const int inner = bid & 255;
    const int m0 = (inner >> 3) * 128;
    const int n0 = (inner & 7) * 128;

    const bf16* A = (which == 0) ? Xq : (which == 1) ? Xk : Xv;
    const bf16* W = (which == 0) ? Wq : (which == 1) ? Wk : Wv;
    const float* bias = (which == 0) ? bq : (which == 1) ? bk : bv;
    const float scale = (which == 0) ? 0.18033688011112042f : 1.0f;

    const int tid = threadIdx.x;
    const int wv = tid >> 6, lane = tid & 63, quad = lane >> 4, l16 = lane & 15;
    const int wr = (wv >> 1) * 64, wc = (wv & 1) * 64;

    __shared__ bf16 As[2][128 * 32];
    __shared__ bf16 Bs[2][128 * 32];

    f32x4 acc[4][4];
#pragma unroll
    for (int i = 0; i < 4; ++i)
#pragma unroll
        for (int j = 0; j < 4; ++j) acc[i][j] = f32x4{0.f, 0.f, 0.f, 0.f};

    // staging: per call, wave wv fills rows (c*64 + wv*16 .. +16) of a
    // [128][32] bf16 tile. lane -> row +(lane>>2), k-offset (lane&3)*8.
    const int srow = lane >> 2;
    const int sk   = (lane & 3) * 8;

#define GSTAGE(k0, buf)                                                       \
    do {                                                                      \
        _Pragma("unroll")                                                     \
        for (int c = 0; c < 2; ++c) {                                         \
            const int rb = c * 64 + wv * 16;                                  \
            g2l16(A + (size_t)(m0 + rb + srow) * D_ + (k0) + sk,              \
                  &As[buf][rb * 32]);                                         \
            g2l16(W + (size_t)(n0 + rb + srow) * D_ + (k0) + sk,              \
                  &Bs[buf][rb * 32]);                                         \
        }                                                                     \
    } while (0)

    GSTAGE(0, 0);
    __syncthreads();   // compiler drains vmcnt before s_barrier: buf0 ready

    int cur = 0;
    for (int ks = 0; ks < 32; ++ks) {
        GSTAGE(((ks + 1) & 31) * 32, cur ^ 1);   // async; drained at barrier

        bf16x8 af[4], bfr[4];
#pragma unroll
        for (int i = 0; i < 4; ++i)
            af[i] = *(const bf16x8*)(&As[cur][(wr + i*16 + l16) * 32 + quad * 8]);
#pragma unroll
        for (int j = 0; j < 4; ++j)
            bfr[j] = *(const bf16x8*)(&Bs[cur][(wc + j*16 + l16) * 32 + quad * 8]);
#pragma unroll
        for (int i = 0; i < 4; ++i)
#pragma unroll
            for (int j = 0; j < 4; ++j)
                acc[i][j] = __builtin_amdgcn_mfma_f32_16x16x32_bf16(
                    af[i], bfr[j], acc[i][j], 0, 0, 0);

        __syncthreads();   // stage of cur^1 done + all waves done with cur
        cur ^= 1;
    }
#undef GSTAGE

    if (which == 2) {
        // V^T pair-interleaved epilogue (identical math to old out_mode 2)
#pragma unroll
        for (int j = 0; j < 4; ++j) {
            const int nn = n0 + wc + j*16 + l16;      // d index
            const float bvv = bias[nn];
            int hh = nn >> 6, dd = nn & (DK_ - 1);
#pragma unroll
            for (int ip = 0; ip < 2; ++ip) {
                const int mlo = m0 + wr + 32*ip + quad*4;
                int bb = mlo >> 11, sl = mlo & (S_ - 1);
                int g0 = (sl & ~31) + ((sl & 15) << 1);
                bf16x8 pk;
#pragma unroll
                for (int r = 0; r < 4; ++r) {
                    pk[2*r]   = (bf16)(acc[2*ip  ][j][r] + bvv);
                    pk[2*r+1] = (bf16)(acc[2*ip+1][j][r] + bvv);
                }
                *(bf16x8*)(Vo + ((size_t)(bb * H_ + hh) * DK_ + dd) * S_ + g0) = pk;
            }
        }
    } else {
        bf16* out = (which == 0) ? Qo : Ko;
#pragma unroll
        for (int i = 0; i < 4; ++i)
#pragma unroll
            for (int j = 0; j < 4; ++j) {
                const int nn = n0 + wc + j*16 + l16;
                const float bvv = bias[nn];
                const int mm0 = m0 + wr + i*16 + quad*4;
                int hh = nn >> 6, dd = nn & (DK_ - 1);
#pragma unroll
                for (int r = 0; r < 4; ++r) {
                    const int mm = mm0 + r;
                    int bb = mm >> 11, ss = mm & (S_ - 1);
                    out[((size_t)(bb * H_ + hh) * S_ + ss) * DK_ + dd] =
                        (bf16)((acc[i][j][r] + bvv) * scale);
                }
            }
    }
}

// ---------------------------------------------------------------------------
// 128x128-tile bf16 GEMM (final output projection only). a_headsplit A,
// fp32 flat out. Unchanged from prior rounds.
// ---------------------------------------------------------------------------
__global__ __launch_bounds__(256)
void gemm128(const bf16* __restrict__ A, const bf16* __restrict__ W,
             const float* __restrict__ bias, float* __restrict__ out)
{
    const int m0 = blockIdx.x * 128, n0 = blockIdx.y * 128;
    const int tid = threadIdx.x;
    const int wv = tid >> 6, lane = tid & 63, quad = lane >> 4, l16 = lane & 15;
    const int wr = (wv >> 1) * 64, wc = (wv & 1) * 64;

    __shared__ bf16 As[128 * 32];
    __shared__ bf16 Bs[128 * 32];

    f32x4 acc[4][4];
#pragma unroll
    for (int i = 0; i < 4; ++i)
#pragma unroll
        for (int j = 0; j < 4; ++j) acc[i][j] = f32x4{0.f, 0.f, 0.f, 0.f};

    const int srow = tid >> 2;
    const int scol = (tid & 3) * 8;

    for (int k0 = 0; k0 < D_; k0 += 32) {
        bf16x8 av[2], bw[2];
#pragma unroll
        for (int c = 0; c < 2; ++c) {
            const int row = c * 64 + srow;
            const int k   = k0 + scol;
            int m = m0 + row, bb = m >> 11, ss = m & (S_ - 1);
            int hh = k >> 6, dd = k & (DK_ - 1);
            av[c] = ld8(A + (((size_t)(bb * H_ + hh) * S_ + ss) * DK_ + dd));
            bw[c] = ld8(W + (size_t)(n0 + row) * D_ + k);
        }
        __syncthreads();
#pragma unroll
        for (int c = 0; c < 2; ++c) {
            const int e = c * 2048 + tid * 8;
            *(bf16x8*)(As + e) = av[c];
            *(bf16x8*)(Bs + e) = bw[c];
        }
        __syncthreads();

        bf16x8 af[4], bfr[4];
#pragma unroll
        for (int i = 0; i < 4; ++i)
            af[i] = *(const bf16x8*)(As + (wr + i*16 + l16) * 32 + quad * 8);
#pragma unroll
        for (int j = 0; j < 4; ++j)
            bfr[j] = *(const bf16x8*)(Bs + (wc + j*16 + l16) * 32 + quad * 8);
#pragma unroll
        for (int i = 0; i < 4; ++i)
#pragma unroll
            for (int j = 0; j < 4; ++j)
                acc[i][j] = __builtin_amdgcn_mfma_f32_16x16x32_bf16(
                    af[i], bfr[j], acc[i][j], 0, 0, 0);
    }

#pragma unroll
    for (int i = 0; i < 4; ++i)
#pragma unroll
        for (int j = 0; j < 4; ++j) {
            const int nn = n0 + wc + j*16 + l16;
            const float bvv = bias[nn];
            const int mm0 = m0 + wr + i*16 + quad*4;
#pragma unroll
            for (int r = 0; r < 4; ++r)
                out[(size_t)(mm0 + r) * D_ + nn] = acc[i][j][r] + bvv;
        }
}

// ---------------------------------------------------------------------------
// Context + softmax denominators, fused (unchanged from r7/r12).
// ---------------------------------------------------------------------------
__global__ __launch_bounds__(256)
void attn_ctx(const bf16* __restrict__ Q, const bf16* __restrict__ K,
              const bf16* __restrict__ Vt, float* __restrict__ Li,
              bf16* __restrict__ ctxOut)
{
    // 1024 blocks; bid%8 = XCD; each XCD gets 128 consecutive semantic idx
    // = 4 full (h,b) groups -> K/V (512KB each) L2-resident per XCD.
    const int bid = blockIdx.x;
    const int l   = (bid & 7) * 128 + (bid >> 3);
    const int q0  = (l & 31) * 64;
    const int h   = (l >> 5) & 15;
    const int b   = l >> 9;

    const int tid = threadIdx.x;
    const int wv = tid >> 6, lane = tid & 63, quad = lane >> 4, l16 = lane & 15;

    __shared__ bf16 Kl[2][4096];   // [buf][64 j][64 dk]  128B rows, swizzled
    __shared__ bf16 Vl[2][4096];   // [buf][64 d][64 pos] 128B rows, swizzled

    const size_t hb = (size_t)(b * H_ + h) * S_;
    const int qw = q0 + wv * 16;   // this wave's 16 q-rows

    bf16x8 qf0, qf1;
    {
        const bf16* qrow = Q + (hb + qw + l16) * DK_;
        qf0 = ld8(qrow + quad*8);
        qf1 = ld8(qrow + 32 + quad*8);
    }
    const char* Kbc = (const char*)(K  + hb * DK_);
    const char* Vbc = (const char*)(Vt + hb * DK_);  // row d at +d*S*2B

    f32x4 cacc[4];      // [db]  C[dk = db*16+quad*4+r][q = l16]
#pragma unroll
    for (int db = 0; db < 4; ++db) cacc[db] = f32x4{0.f,0.f,0.f,0.f};
    float lsum = 0.f;

    const int rbK  = wv * 16;
    const int rlan = lane >> 3;
    const int off  = (((lane & 7) ^ rlan) << 4);

#define STAGE(jc, buf)                                                        \
    do {                                                                      \
        const size_t jb = (size_t)(jc) * 64;                                  \
        g2l16(Kbc + (jb + rbK + rlan) * 128 + off,      &Kl[buf][rbK*64]);    \
        g2l16(Kbc + (jb + rbK + 8 + rlan) * 128 + off,  &Kl[buf][(rbK+8)*64]);\
        g2l16(Vbc + (size_t)(rbK + rlan) * (S_*2) + jb*2 + off,               \
              &Vl[buf][rbK*64]);                                              \
        g2l16(Vbc + (size_t)(rbK + 8 + rlan) * (S_*2) + jb*2 + off,           \
              &Vl[buf][(rbK+8)*64]);                                          \
    } while (0)

    STAGE(0, 0);
    __syncthreads();   // drains vmcnt(0): buf0 ready

    int cur = 0;
    const int sw = (l16 & 7) << 4;   // read-side XOR key (row&7 == l16&7)
    for (int jc = 0; jc < 32; ++jc) {
        STAGE((jc + 1) & 31, cur ^ 1);   // async; drained at the barrier

        const char* kb = (const char*)&Kl[cur][0];
        const char* vb = (const char*)&Vl[cur][0];

        // QK^T: 4 j-tiles of 16
        f32x4 sc[4];
#pragma unroll
        for (int t = 0; t < 4; ++t) {
            const char* kr = kb + (t*16 + l16) * 128;
            bf16x8 ka = *(const bf16x8*)(kr + ((quad*16) ^ sw));
            bf16x8 kbv = *(const bf16x8*)(kr + ((64 + quad*16) ^ sw));
            f32x4 z = {0.f,0.f,0.f,0.f};
            z = __builtin_amdgcn_mfma_f32_16x16x32_bf16(ka, qf0, z, 0, 0, 0);
            sc[t] = __builtin_amdgcn_mfma_f32_16x16x32_bf16(kbv, qf1, z, 0, 0, 0);
        }

        float ex[4][4];
#pragma unroll
        for (int t = 0; t < 4; ++t)
#pragma unroll
            for (int r = 0; r < 4; ++r)
                ex[t][r] = __builtin_amdgcn_exp2f(fminf(sc[t][r], 86.f));
#pragma unroll
        for (int t = 0; t < 4; ++t)
            lsum += (ex[t][0] + ex[t][1]) + (ex[t][2] + ex[t][3]);

        bf16x8 pa0, pa1;
#pragma unroll
        for (int r = 0; r < 4; ++r) {
            pa0[2*r]   = (bf16)ex[0][r];
            pa0[2*r+1] = (bf16)ex[1][r];
            pa1[2*r]   = (bf16)ex[2][r];
            pa1[2*r+1] = (bf16)ex[3][r];
        }

#pragma unroll
        for (int db = 0; db < 4; ++db) {
            const char* vr = vb + (db*16 + l16) * 128;
            bf16x8 va0 = *(const bf16x8*)(vr + ((quad*16) ^ sw));
            bf16x8 va1 = *(const bf16x8*)(vr + ((64 + quad*16) ^ sw));
            cacc[db] = __builtin_amdgcn_mfma_f32_16x16x32_bf16(
                va0, pa0, cacc[db], 0, 0, 0);
            cacc[db] = __builtin_amdgcn_mfma_f32_16x16x32_bf16(
                va1, pa1, cacc[db], 0, 0, 0);
        }

        __syncthreads();   // drains stage vmcnt + all waves done with cur
        cur ^= 1;
    }
#undef STAGE

    lsum += __shfl_xor(lsum, 16);
    lsum += __shfl_xor(lsum, 32);
    const float linv = 1.0f / fmaxf(lsum, 1e-30f);
    if (lane < 16) Li[hb + qw + lane] = lsum;

#pragma unroll
    for (int db = 0; db < 4; ++db) {
        bf16x4 pk;
#pragma unroll
        for (int r = 0; r < 4; ++r) pk[r] = (bf16)(cacc[db][r] * linv);
        *(bf16x4*)(ctxOut + (hb + qw + l16) * DK_ + db*16 + quad*4) = pk;
    }
}

// ---------------------------------------------------------------------------
// Head-mean attention weights (unchanged from r12: r7 geometry + explicit
// K-batch + Q-prefetch pipeline; plateaued ~71us across 5 variants).
// ---------------------------------------------------------------------------
__global__ __launch_bounds__(256)
void attn_weights(const bf16* __restrict__ Q, const bf16* __restrict__ K,
                  const float* __restrict__ Li, float* __restrict__ attnOut)
{
    const int bid = blockIdx.x;
    const int l   = (bid & 7) * 64 + (bid >> 3);
    const int q0  = (l & 31) * 64;
    const int b   = (l >> 5) & 1;
    const int j0  = (l >> 6) * 256;

    const int tid = threadIdx.x;
    const int wv = tid >> 6, lane = tid & 63, quad = lane >> 4, l16 = lane & 15;

    __shared__ float linv[H_][64];
#pragma unroll
    for (int i = 0; i < 4; ++i) {
        int idx = tid * 4 + i;
        int hh = idx >> 6, row = idx & 63;
        linv[hh][row] = (1.0f / H_) /
            fmaxf(Li[(size_t)(b * H_ + hh) * S_ + q0 + row], 1e-30f);
    }
    __syncthreads();

    f32x4 asum[4][4];
#pragma unroll
    for (int qt = 0; qt < 4; ++qt)
#pragma unroll
        for (int t = 0; t < 4; ++t) asum[qt][t] = f32x4{0.f,0.f,0.f,0.f};

    bf16x8 qc[4][2];
    {
        const size_t hb0 = (size_t)(b * H_) * S_;
#pragma unroll
        for (int qt = 0; qt < 4; ++qt) {
            const bf16* qrow = Q + (hb0 + q0 + qt*16 + l16) * DK_;
            qc[qt][0] = ld8(qrow + quad*8);
            qc[qt][1] = ld8(qrow + 32 + quad*8);
        }
    }

    for (int h = 0; h < H_; ++h) {
        const size_t hb = (size_t)(b * H_ + h) * S_;

        bf16x8 kA[4], kB[4];
#pragma unroll
        for (int t = 0; t < 4; ++t) {
            const bf16* krow = K + (hb + (size_t)(j0 + wv*64 + t*16 + l16)) * DK_;
            kA[t] = ld8(krow + quad*8);
            kB[t] = ld8(krow + 32 + quad*8);
        }

        bf16x8 qn[4][2];
        {
            const size_t hbn = (size_t)(b * H_ + ((h + 1) & 15)) * S_;
#pragma unroll
            for (int qt = 0; qt < 4; ++qt) {
                const bf16* qrow = Q + (hbn + q0 + qt*16 + l16) * DK_;
                qn[qt][0] = ld8(qrow + quad*8);
                qn[qt][1] = ld8(qrow + 32 + quad*8);
            }
        }

        float lv[4];
#pragma unroll
        for (int qt = 0; qt < 4; ++qt) lv[qt] = linv[h][qt*16 + l16];

#pragma unroll
        for (int t = 0; t < 4; ++t)
#pragma unroll
            for (int qt = 0; qt < 4; ++qt) {
                f32x4 z = {0.f,0.f,0.f,0.f};
                z = __builtin_amdgcn_mfma_f32_16x16x32_bf16(kA[t], qc[qt][0], z, 0, 0, 0);
                f32x4 s = __builtin_amdgcn_mfma_f32_16x16x32_bf16(kB[t], qc[qt][1], z, 0, 0, 0);
#pragma unroll
                for (int r = 0; r < 4; ++r)
                    asum[qt][t][r] += __builtin_amdgcn_exp2f(fminf(s[r], 86.f)) * lv[qt];
            }

#pragma unroll
        for (int qt = 0; qt < 4; ++qt) {
            qc[qt][0] = qn[qt][0];
            qc[qt][1] = qn[qt][1];
        }
    }

#pragma unroll
    for (int qt = 0; qt < 4; ++qt)
#pragma unroll
        for (int t = 0; t < 4; ++t)
            *(f32x4*)(attnOut + ((size_t)b * S_ + q0 + qt*16 + l16) * S_
                      + j0 + wv*64 + t*16 + quad*4) = asum[qt][t];
}

// ---------------------------------------------------------------------------
extern "C" void kernel_launch(void* const* d_in, const int* in_sizes, int n_in,
                              void* d_out, int out_size, void* d_ws, size_t ws_size,
                              hipStream_t stream)
{
    (void)in_sizes; (void)n_in; (void)out_size; (void)ws_size;

    const float* query = (const float*)d_in[0];
    const float* key_t = (const float*)d_in[1];
    const float* value = (const float*)d_in[2];
    const float* Wq = (const float*)d_in[3];
    const float* bq = (const float*)d_in[4];
    const float* Wk = (const float*)d_in[5];
    const float* bk = (const float*)d_in[6];
    const float* Wv = (const float*)d_in[7];
    const float* bv = (const float*)d_in[8];
    const float* Wo = (const float*)d_in[9];
    const float* bo = (const float*)d_in[10];

    float* out     = (float*)d_out;                  // (B,S,D) fp32
    float* attnOut = out + (size_t)B_ * S_ * D_;     // (B,S,S) fp32

    const size_t nX = (size_t)B_ * S_ * D_;
    const size_t nW = (size_t)D_ * D_;

    // d_out doubles as scratch for bf16 X-converts (dead before overwrites)
    bf16* Xqb = (bf16*)d_out;
    bf16* Xkb = Xqb + nX;
    bf16* Xvb = Xkb + nX;

    // ws: Qh,Kh,VtH (25.2MB) + Wob (2.1MB) + Li (0.26MB) + [Wqb/Wkb/Wvb
    // overlaid by CtxH (8.4MB) -- W converts are dead before attn_ctx runs].
    bf16* Qh  = (bf16*)d_ws;
    bf16* Kh  = Qh + nX;
    bf16* VtH = Kh + nX;                 // V^T (B,H,DK,S), pair-interleaved
    bf16* Wob = VtH + nX;
    float* Li = (float*)(Wob + nW);
    bf16* Wqb = (bf16*)(Li + (size_t)B_ * H_ * S_);
    bf16* Wkb = Wqb + nW;
    bf16* Wvb = Wkb + nW;
    bf16* CtxH = Wqb;                                // overlays dead W converts

    cvt_all<<<8192, 256, 0, stream>>>(query, key_t, value, Wq, Wk, Wv, Wo,
                                      Xqb, Xkb, Xvb, Wqb, Wkb, Wvb, Wob);
    // Q/K/V projections in ONE launch: 768 blocks = 3 blocks/CU (was 3x256
    // = 1 block/CU each), async-LDS staged. Q pre-scaled by 0.125*log2(e).
    gemm_qkv<<<768, 256, 0, stream>>>(Xqb, Xkb, Xvb, Wqb, Wkb, Wvb,
                                      bq, bk, bv, Qh, Kh, VtH);
    attn_ctx    <<<1024, 256, 0, stream>>>(Qh, Kh, VtH, Li, CtxH);
    attn_weights<<<512, 256, 0, stream>>>(Qh, Kh, Li, attnOut);
    dim3 gg(M_/128, D_/128);
    gemm128<<<gg, 256, 0, stream>>>(CtxH, Wob, bo, out);
}

// Round 14
// 311.931 us; speedup vs baseline: 1.2058x; 1.0173x over previous
//
#include <hip/hip_runtime.h>

// Problem constants (B,S,D,H from reference)
#define B_ 2
#define S_ 2048
#define D_ 1024
#define H_ 16
#define DK_ 64
#define M_ (B_ * S_)      // 4096 rows in the projection GEMMs

typedef __bf16 bf16;
typedef __attribute__((ext_vector_type(8))) __bf16 bf16x8;
typedef __attribute__((ext_vector_type(4))) __bf16 bf16x4;
typedef __attribute__((ext_vector_type(4))) float f32x4;

static __device__ __forceinline__ bf16x8 ld8(const bf16* p) {
    return *(const bf16x8*)p;   // 16B aligned by construction
}

// Async global->LDS, 16B per lane. LDS dest = wave-uniform base + lane*16
// (linear); global src is per-lane.
static __device__ __forceinline__ void g2l16(const void* g, void* l) {
    __builtin_amdgcn_global_load_lds(
        (const __attribute__((address_space(1))) unsigned int*)g,
        (__attribute__((address_space(3))) unsigned int*)l, 16, 0, 0);
}

// ---------------------------------------------------------------------------
// Elementwise fp32 -> bf16 for the 3 X inputs (into d_out scratch) and the
// 4 weight matrices (into ws). Block mapping: 3*2048 X-blocks + 4*512 W-blocks.
// ---------------------------------------------------------------------------
__global__ __launch_bounds__(256)
void cvt_all(const float* __restrict__ xq, const float* __restrict__ xk,
             const float* __restrict__ xv, const float* __restrict__ wq,
             const float* __restrict__ wk, const float* __restrict__ wv,
             const float* __restrict__ wo, bf16* __restrict__ xqo,
             bf16* __restrict__ xko, bf16* __restrict__ xvo,
             bf16* __restrict__ wqo, bf16* __restrict__ wko,
             bf16* __restrict__ wvo, bf16* __restrict__ woo)
{
    const int bx = blockIdx.x;
    const float* s; bf16* d; size_t base;
    if (bx < 6144) {
        int a = bx >> 11;
        s = (a == 0) ? xq : (a == 1) ? xk : xv;
        d = (a == 0) ? xqo : (a == 1) ? xko : xvo;
        base = (size_t)(bx & 2047) * 2048;
    } else {
        int a = (bx - 6144) >> 9;
        s = (a == 0) ? wq : (a == 1) ? wk : (a == 2) ? wv : wo;
        d = (a == 0) ? wqo : (a == 1) ? wko : (a == 2) ? wvo : woo;
        base = (size_t)((bx - 6144) & 511) * 2048;
    }
    size_t i = base + (size_t)threadIdx.x * 8;
    f32x4 a4 = *(const f32x4*)(s + i);
    f32x4 b4 = *(const f32x4*)(s + i + 4);
    bf16x8 r;
    r[0]=(bf16)a4[0]; r[1]=(bf16)a4[1]; r[2]=(bf16)a4[2]; r[3]=(bf16)a4[3];
    r[4]=(bf16)b4[0]; r[5]=(bf16)b4[1]; r[6]=(bf16)b4[2]; r[7]=(bf16)b4[3];
    *(bf16x8*)(d + i) = r;
}

// ---------------------------------------------------------------------------
// Batched Q/K/V projection GEMM (unchanged from r13; refcheck'd).
// ONE 768-block launch (3 blocks/CU) with async global_load_lds staging into
// double-buffered LDS, 1 barrier per K-step.
// which=0: Q out (headsplit bf16, scale 0.125*log2e folded for exp2)
// which=1: K out (headsplit bf16)
// which=2: V out (B,H,DK,S) PAIR-INTERLEAVED: pos = 2*(j&15) + (j>>4).
// ---------------------------------------------------------------------------
__global__ __launch_bounds__(256)
void gemm_qkv(const bf16* __restrict__ Xq, const bf16* __restrict__ Xk,
              const bf16* __restrict__ Xv, const bf16* __restrict__ Wq,
              const bf16* __restrict__ Wk, const bf16* __restrict__ Wv,
              const float* __restrict__ bq, const float* __restrict__ bk,
              const float* __restrict__ bv, bf16* __restrict__ Qo,
              bf16* __restrict__ Ko, bf16* __restrict__ Vo)
{
    const int bid = blockIdx.x;
    const int which = bid >> 8;          // 0=Q 1=K 2=V
    const int inner = bid & 255;
    const int m0 = (inner >> 3) * 128;
    const int n0 = (inner & 7) * 128;

    const bf16* A = (which == 0) ? Xq : (which == 1) ? Xk : Xv;
    const bf16* W = (which == 0) ? Wq : (which == 1) ? Wk : Wv;
    const float* bias = (which == 0) ? bq : (which == 1) ? bk : bv;
    const float scale = (which == 0) ? 0.18033688011112042f : 1.0f;

    const int tid = threadIdx.x;
    const int wv = tid >> 6, lane = tid & 63, quad = lane >> 4, l16 = lane & 15;
    const int wr = (wv >> 1) * 64, wc = (wv & 1) * 64;

    __shared__ bf16 As[2][128 * 32];
    __shared__ bf16 Bs[2][128 * 32];

    f32x4 acc[4][4];
#pragma unroll
    for (int i = 0; i < 4; ++i)
#pragma unroll
        for (int j = 0; j < 4; ++j) acc[i][j] = f32x4{0.f, 0.f, 0.f, 0.f};

    const int srow = lane >> 2;
    const int sk   = (lane & 3) * 8;

#define GSTAGE(k0, buf)                                                       \
    do {                                                                      \
        _Pragma("unroll")                                                     \
        for (int c = 0; c < 2; ++c) {                                         \
            const int rb = c * 64 + wv * 16;                                  \
            g2l16(A + (size_t)(m0 + rb + srow) * D_ + (k0) + sk,              \
                  &As[buf][rb * 32]);                                         \
            g2l16(W + (size_t)(n0 + rb + srow) * D_ + (k0) + sk,              \
                  &Bs[buf][rb * 32]);                                         \
        }                                                                     \
    } while (0)

    GSTAGE(0, 0);
    __syncthreads();   // compiler drains vmcnt before s_barrier: buf0 ready

    int cur = 0;
    for (int ks = 0; ks < 32; ++ks) {
        GSTAGE(((ks + 1) & 31) * 32, cur ^ 1);   // async; drained at barrier

        bf16x8 af[4], bfr[4];
#pragma unroll
        for (int i = 0; i < 4; ++i)
            af[i] = *(const bf16x8*)(&As[cur][(wr + i*16 + l16) * 32 + quad * 8]);
#pragma unroll
        for (int j = 0; j < 4; ++j)
            bfr[j] = *(const bf16x8*)(&Bs[cur][(wc + j*16 + l16) * 32 + quad * 8]);
#pragma unroll
        for (int i = 0; i < 4; ++i)
#pragma unroll
            for (int j = 0; j < 4; ++j)
                acc[i][j] = __builtin_amdgcn_mfma_f32_16x16x32_bf16(
                    af[i], bfr[j], acc[i][j], 0, 0, 0);

        __syncthreads();   // stage of cur^1 done + all waves done with cur
        cur ^= 1;
    }
#undef GSTAGE

    if (which == 2) {
#pragma unroll
        for (int j = 0; j < 4; ++j) {
            const int nn = n0 + wc + j*16 + l16;      // d index
            const float bvv = bias[nn];
            int hh = nn >> 6, dd = nn & (DK_ - 1);
#pragma unroll
            for (int ip = 0; ip < 2; ++ip) {
                const int mlo = m0 + wr + 32*ip + quad*4;
                int bb = mlo >> 11, sl = mlo & (S_ - 1);
                int g0 = (sl & ~31) + ((sl & 15) << 1);
                bf16x8 pk;
#pragma unroll
                for (int r = 0; r < 4; ++r) {
                    pk[2*r]   = (bf16)(acc[2*ip  ][j][r] + bvv);
                    pk[2*r+1] = (bf16)(acc[2*ip+1][j][r] + bvv);
                }
                *(bf16x8*)(Vo + ((size_t)(bb * H_ + hh) * DK_ + dd) * S_ + g0) = pk;
            }
        }
    } else {
        bf16* out = (which == 0) ? Qo : Ko;
#pragma unroll
        for (int i = 0; i < 4; ++i)
#pragma unroll
            for (int j = 0; j < 4; ++j) {
                const int nn = n0 + wc + j*16 + l16;
                const float bvv = bias[nn];
                const int mm0 = m0 + wr + i*16 + quad*4;
                int hh = nn >> 6, dd = nn & (DK_ - 1);
#pragma unroll
                for (int r = 0; r < 4; ++r) {
                    const int mm = mm0 + r;
                    int bb = mm >> 11, ss = mm & (S_ - 1);
                    out[((size_t)(bb * H_ + hh) * S_ + ss) * DK_ + dd] =
                        (bf16)((acc[i][j][r] + bvv) * scale);
                }
            }
    }
}

// ---------------------------------------------------------------------------
// Output projection GEMM. r13 post-mortem: old 128x128 grid = 256 blocks =
// 1 block/CU = 1 wave/SIMD (the same disease gemm_qkv cured). Now 64x128
// tiles -> 512 blocks = 2 blocks/CU, async global_load_lds double-buffered
// staging (gemm_qkv's verified structure). A is headsplit ctx (B,H,S,DK);
// out fp32 flat (M,D). XCD swizzle: each XCD owns 8 m-panels x all n
// (W 2MB L2-resident per XCD).
// ---------------------------------------------------------------------------
__global__ __launch_bounds__(256)
void gemm_out(const bf16* __restrict__ A, const bf16* __restrict__ W,
              const float* __restrict__ bias, float* __restrict__ out)
{
    const int bid = blockIdx.x;
    const int l   = (bid & 7) * 64 + (bid >> 3);   // XCD-chunked, bijective
    const int m0 = (l >> 3) * 64;
    const int n0 = (l & 7) * 128;

    const int tid = threadIdx.x;
    const int wv = tid >> 6, lane = tid & 63, quad = lane >> 4, l16 = lane & 15;
    const int wr = (wv >> 1) * 32, wc = (wv & 1) * 64;

    __shared__ bf16 As[2][64 * 32];    // 4KB per buf
    __shared__ bf16 Bs[2][128 * 32];   // 8KB per buf

    f32x4 acc[2][4];
#pragma unroll
    for (int i = 0; i < 2; ++i)
#pragma unroll
        for (int j = 0; j < 4; ++j) acc[i][j] = f32x4{0.f, 0.f, 0.f, 0.f};

    // A staging: per-lane row (in 16-row wave stripe) + k-slot; A is
    // headsplit, so bb/ss are fixed per lane; hh/dd vary with k0.
    const int arow = wv * 16 + (lane >> 2);        // tile row 0..63
    const int sk   = (lane & 3) * 8;               // k offset 0/8/16/24
    const int am   = m0 + arow;
    const size_t abase = ((size_t)((am >> 11) * H_) * S_ + (am & (S_ - 1))) * DK_;

#define OSTAGE(k0, buf)                                                       \
    do {                                                                      \
        const int kk = (k0) + sk;                                             \
        g2l16(A + abase + (size_t)(kk >> 6) * (S_ * DK_) + (kk & (DK_ - 1)),  \
              &As[buf][(wv * 16) * 32]);                                      \
        _Pragma("unroll")                                                     \
        for (int c = 0; c < 2; ++c) {                                         \
            const int rb = wv * 32 + c * 16;                                  \
            g2l16(W + (size_t)(n0 + rb + (lane >> 2)) * D_ + (k0) + sk,       \
                  &Bs[buf][rb * 32]);                                         \
        }                                                                     \
    } while (0)

    OSTAGE(0, 0);
    __syncthreads();   // buf0 ready

    int cur = 0;
    for (int ks = 0; ks < 32; ++ks) {
        OSTAGE(((ks + 1) & 31) * 32, cur ^ 1);   // async; drained at barrier

        bf16x8 af[2], bfr[4];
#pragma unroll
        for (int i = 0; i < 2; ++i)
            af[i] = *(const bf16x8*)(&As[cur][(wr + i*16 + l16) * 32 + quad * 8]);
#pragma unroll
        for (int j = 0; j < 4; ++j)
            bfr[j] = *(const bf16x8*)(&Bs[cur][(wc + j*16 + l16) * 32 + quad * 8]);
#pragma unroll
        for (int i = 0; i < 2; ++i)
#pragma unroll
            for (int j = 0; j < 4; ++j)
                acc[i][j] = __builtin_amdgcn_mfma_f32_16x16x32_bf16(
                    af[i], bfr[j], acc[i][j], 0, 0, 0);

        __syncthreads();
        cur ^= 1;
    }
#undef OSTAGE

#pragma unroll
    for (int i = 0; i < 2; ++i)
#pragma unroll
        for (int j = 0; j < 4; ++j) {
            const int nn = n0 + wc + j*16 + l16;
            const float bvv = bias[nn];
            const int mm0 = m0 + wr + i*16 + quad*4;
#pragma unroll
            for (int r = 0; r < 4; ++r)
                out[(size_t)(mm0 + r) * D_ + nn] = acc[i][j][r] + bvv;
        }
}

// ---------------------------------------------------------------------------
// Context + softmax denominators, fused (unchanged from r7/r13).
// ---------------------------------------------------------------------------
__global__ __launch_bounds__(256)
void attn_ctx(const bf16* __restrict__ Q, const bf16* __restrict__ K,
              const bf16* __restrict__ Vt, float* __restrict__ Li,
              bf16* __restrict__ ctxOut)
{
    // 1024 blocks; bid%8 = XCD; each XCD gets 128 consecutive semantic idx
    // = 4 full (h,b) groups -> K/V (512KB each) L2-resident per XCD.
    const int bid = blockIdx.x;
    const int l   = (bid & 7) * 128 + (bid >> 3);
    const int q0  = (l & 31) * 64;
    const int h   = (l >> 5) & 15;
    const int b   = l >> 9;

    const int tid = threadIdx.x;
    const int wv = tid >> 6, lane = tid & 63, quad = lane >> 4, l16 = lane & 15;

    __shared__ bf16 Kl[2][4096];   // [buf][64 j][64 dk]  128B rows, swizzled
    __shared__ bf16 Vl[2][4096];   // [buf][64 d][64 pos] 128B rows, swizzled

    const size_t hb = (size_t)(b * H_ + h) * S_;
    const int qw = q0 + wv * 16;   // this wave's 16 q-rows

    bf16x8 qf0, qf1;
    {
        const bf16* qrow = Q + (hb + qw + l16) * DK_;
        qf0 = ld8(qrow + quad*8);
        qf1 = ld8(qrow + 32 + quad*8);
    }
    const char* Kbc = (const char*)(K  + hb * DK_);
    const char* Vbc = (const char*)(Vt + hb * DK_);  // row d at +d*S*2B

    f32x4 cacc[4];      // [db]  C[dk = db*16+quad*4+r][q = l16]
#pragma unroll
    for (int db = 0; db < 4; ++db) cacc[db] = f32x4{0.f,0.f,0.f,0.f};
    float lsum = 0.f;

    const int rbK  = wv * 16;
    const int rlan = lane >> 3;
    const int off  = (((lane & 7) ^ rlan) << 4);

#define STAGE(jc, buf)                                                        \
    do {                                                                      \
        const size_t jb = (size_t)(jc) * 64;                                  \
        g2l16(Kbc + (jb + rbK + rlan) * 128 + off,      &Kl[buf][rbK*64]);    \
        g2l16(Kbc + (jb + rbK + 8 + rlan) * 128 + off,  &Kl[buf][(rbK+8)*64]);\
        g2l16(Vbc + (size_t)(rbK + rlan) * (S_*2) + jb*2 + off,               \
              &Vl[buf][rbK*64]);                                              \
        g2l16(Vbc + (size_t)(rbK + 8 + rlan) * (S_*2) + jb*2 + off,           \
              &Vl[buf][(rbK+8)*64]);                                          \
    } while (0)

    STAGE(0, 0);
    __syncthreads();   // drains vmcnt(0): buf0 ready

    int cur = 0;
    const int sw = (l16 & 7) << 4;   // read-side XOR key (row&7 == l16&7)
    for (int jc = 0; jc < 32; ++jc) {
        STAGE((jc + 1) & 31, cur ^ 1);   // async; drained at the barrier

        const char* kb = (const char*)&Kl[cur][0];
        const char* vb = (const char*)&Vl[cur][0];

        // QK^T: 4 j-tiles of 16
        f32x4 sc[4];
#pragma unroll
        for (int t = 0; t < 4; ++t) {
            const char* kr = kb + (t*16 + l16) * 128;
            bf16x8 ka = *(const bf16x8*)(kr + ((quad*16) ^ sw));
            bf16x8 kbv = *(const bf16x8*)(kr + ((64 + quad*16) ^ sw));
            f32x4 z = {0.f,0.f,0.f,0.f};
            z = __builtin_amdgcn_mfma_f32_16x16x32_bf16(ka, qf0, z, 0, 0, 0);
            sc[t] = __builtin_amdgcn_mfma_f32_16x16x32_bf16(kbv, qf1, z, 0, 0, 0);
        }

        float ex[4][4];
#pragma unroll
        for (int t = 0; t < 4; ++t)
#pragma unroll
            for (int r = 0; r < 4; ++r)
                ex[t][r] = __builtin_amdgcn_exp2f(fminf(sc[t][r], 86.f));
#pragma unroll
        for (int t = 0; t < 4; ++t)
            lsum += (ex[t][0] + ex[t][1]) + (ex[t][2] + ex[t][3]);

        bf16x8 pa0, pa1;
#pragma unroll
        for (int r = 0; r < 4; ++r) {
            pa0[2*r]   = (bf16)ex[0][r];
            pa0[2*r+1] = (bf16)ex[1][r];
            pa1[2*r]   = (bf16)ex[2][r];
            pa1[2*r+1] = (bf16)ex[3][r];
        }

#pragma unroll
        for (int db = 0; db < 4; ++db) {
            const char* vr = vb + (db*16 + l16) * 128;
            bf16x8 va0 = *(const bf16x8*)(vr + ((quad*16) ^ sw));
            bf16x8 va1 = *(const bf16x8*)(vr + ((64 + quad*16) ^ sw));
            cacc[db] = __builtin_amdgcn_mfma_f32_16x16x32_bf16(
                va0, pa0, cacc[db], 0, 0, 0);
            cacc[db] = __builtin_amdgcn_mfma_f32_16x16x32_bf16(
                va1, pa1, cacc[db], 0, 0, 0);
        }

        __syncthreads();   // drains stage vmcnt + all waves done with cur
        cur ^= 1;
    }
#undef STAGE

    lsum += __shfl_xor(lsum, 16);
    lsum += __shfl_xor(lsum, 32);
    const float linv = 1.0f / fmaxf(lsum, 1e-30f);
    if (lane < 16) Li[hb + qw + lane] = lsum;

#pragma unroll
    for (int db = 0; db < 4; ++db) {
        bf16x4 pk;
#pragma unroll
        for (int r = 0; r < 4; ++r) pk[r] = (bf16)(cacc[db][r] * linv);
        *(bf16x4*)(ctxOut + (hb + qw + l16) * DK_ + db*16 + quad*4) = pk;
    }
}

// ---------------------------------------------------------------------------
// Head-mean attention weights (r12 pipeline). Change vs r13: launch_bounds
// min-waves=2. The pipeline needs ~180 live VGPRs (asum 64 + qc/qn 64 +
// K 32 + temps) but default bounds let the compiler squeeze to 124
// (targeting 4 waves/SIMD that the 512-block grid can never make resident).
// min-waves=2 raises the budget to 256 so the full ILP pipeline
// materializes. (Opposite of r4's mistake: relaxing to match real
// occupancy, not capping to force it.)
// ---------------------------------------------------------------------------
__global__ __launch_bounds__(256, 2)
void attn_weights(const bf16* __restrict__ Q, const bf16* __restrict__ K,
                  const float* __restrict__ Li, float* __restrict__ attnOut)
{
    const int bid = blockIdx.x;
    const int l   = (bid & 7) * 64 + (bid >> 3);
    const int q0  = (l & 31) * 64;
    const int b   = (l >> 5) & 1;
    const int j0  = (l >> 6) * 256;

    const int tid = threadIdx.x;
    const int wv = tid >> 6, lane = tid & 63, quad = lane >> 4, l16 = lane & 15;

    __shared__ float linv[H_][64];
#pragma unroll
    for (int i = 0; i < 4; ++i) {
        int idx = tid * 4 + i;
        int hh = idx >> 6, row = idx & 63;
        linv[hh][row] = (1.0f / H_) /
            fmaxf(Li[(size_t)(b * H_ + hh) * S_ + q0 + row], 1e-30f);
    }
    __syncthreads();

    f32x4 asum[4][4];
#pragma unroll
    for (int qt = 0; qt < 4; ++qt)
#pragma unroll
        for (int t = 0; t < 4; ++t) asum[qt][t] = f32x4{0.f,0.f,0.f,0.f};

    bf16x8 qc[4][2];
    {
        const size_t hb0 = (size_t)(b * H_) * S_;
#pragma unroll
        for (int qt = 0; qt < 4; ++qt) {
            const bf16* qrow = Q + (hb0 + q0 + qt*16 + l16) * DK_;
            qc[qt][0] = ld8(qrow + quad*8);
            qc[qt][1] = ld8(qrow + 32 + quad*8);
        }
    }

    for (int h = 0; h < H_; ++h) {
        const size_t hb = (size_t)(b * H_ + h) * S_;

        bf16x8 kA[4], kB[4];
#pragma unroll
        for (int t = 0; t < 4; ++t) {
            const bf16* krow = K + (hb + (size_t)(j0 + wv*64 + t*16 + l16)) * DK_;
            kA[t] = ld8(krow + quad*8);
            kB[t] = ld8(krow + 32 + quad*8);
        }

        bf16x8 qn[4][2];
        {
            const size_t hbn = (size_t)(b * H_ + ((h + 1) & 15)) * S_;
#pragma unroll
            for (int qt = 0; qt < 4; ++qt) {
                const bf16* qrow = Q + (hbn + q0 + qt*16 + l16) * DK_;
                qn[qt][0] = ld8(qrow + quad*8);
                qn[qt][1] = ld8(qrow + 32 + quad*8);
            }
        }

        float lv[4];
#pragma unroll
        for (int qt = 0; qt < 4; ++qt) lv[qt] = linv[h][qt*16 + l16];

#pragma unroll
        for (int t = 0; t < 4; ++t)
#pragma unroll
            for (int qt = 0; qt < 4; ++qt) {
                f32x4 z = {0.f,0.f,0.f,0.f};
                z = __builtin_amdgcn_mfma_f32_16x16x32_bf16(kA[t], qc[qt][0], z, 0, 0, 0);
                f32x4 s = __builtin_amdgcn_mfma_f32_16x16x32_bf16(kB[t], qc[qt][1], z, 0, 0, 0);
#pragma unroll
                for (int r = 0; r < 4; ++r)
                    asum[qt][t][r] += __builtin_amdgcn_exp2f(fminf(s[r], 86.f)) * lv[qt];
            }

#pragma unroll
        for (int qt = 0; qt < 4; ++qt) {
            qc[qt][0] = qn[qt][0];
            qc[qt][1] = qn[qt][1];
        }
    }

#pragma unroll
    for (int qt = 0; qt < 4; ++qt)
#pragma unroll
        for (int t = 0; t < 4; ++t)
            *(f32x4*)(attnOut + ((size_t)b * S_ + q0 + qt*16 + l16) * S_
                      + j0 + wv*64 + t*16 + quad*4) = asum[qt][t];
}

// ---------------------------------------------------------------------------
extern "C" void kernel_launch(void* const* d_in, const int* in_sizes, int n_in,
                              void* d_out, int out_size, void* d_ws, size_t ws_size,
                              hipStream_t stream)
{
    (void)in_sizes; (void)n_in; (void)out_size; (void)ws_size;

    const float* query = (const float*)d_in[0];
    const float* key_t = (const float*)d_in[1];
    const float* value = (const float*)d_in[2];
    const float* Wq = (const float*)d_in[3];
    const float* bq = (const float*)d_in[4];
    const float* Wk = (const float*)d_in[5];
    const float* bk = (const float*)d_in[6];
    const float* Wv = (const float*)d_in[7];
    const float* bv = (const float*)d_in[8];
    const float* Wo = (const float*)d_in[9];
    const float* bo = (const float*)d_in[10];

    float* out     = (float*)d_out;                  // (B,S,D) fp32
    float* attnOut = out + (size_t)B_ * S_ * D_;     // (B,S,S) fp32

    const size_t nX = (size_t)B_ * S_ * D_;
    const size_t nW = (size_t)D_ * D_;

    // d_out doubles as scratch for bf16 X-converts (dead before overwrites)
    bf16* Xqb = (bf16*)d_out;
    bf16* Xkb = Xqb + nX;
    bf16* Xvb = Xkb + nX;

    // ws: Qh,Kh,VtH (25.2MB) + Wob (2.1MB) + Li (0.26MB) + [Wqb/Wkb/Wvb
    // overlaid by CtxH (8.4MB) -- W converts are dead before attn_ctx runs].
    bf16* Qh  = (bf16*)d_ws;
    bf16* Kh  = Qh + nX;
    bf16* VtH = Kh + nX;                 // V^T (B,H,DK,S), pair-interleaved
    bf16* Wob = VtH + nX;
    float* Li = (float*)(Wob + nW);
    bf16* Wqb = (bf16*)(Li + (size_t)B_ * H_ * S_);
    bf16* Wkb = Wqb + nW;
    bf16* Wvb = Wkb + nW;
    bf16* CtxH = Wqb;                                // overlays dead W converts

    cvt_all<<<8192, 256, 0, stream>>>(query, key_t, value, Wq, Wk, Wv, Wo,
                                      Xqb, Xkb, Xvb, Wqb, Wkb, Wvb, Wob);
    // Q/K/V projections in ONE launch: 768 blocks = 3 blocks/CU.
    gemm_qkv<<<768, 256, 0, stream>>>(Xqb, Xkb, Xvb, Wqb, Wkb, Wvb,
                                      bq, bk, bv, Qh, Kh, VtH);
    attn_ctx    <<<1024, 256, 0, stream>>>(Qh, Kh, VtH, Li, CtxH);
    attn_weights<<<512, 256, 0, stream>>>(Qh, Kh, Li, attnOut);
    // Output projection: 512 blocks (64x128 tiles) = 2 blocks/CU.
    gemm_out<<<512, 256, 0, stream>>>(CtxH, Wob, bo, out);
}